// Round 7
// baseline (350.367 us; speedup 1.0000x reference)
//
#include <hip/hip_runtime.h>
#include <cstdint>
#include <cstddef>

// Problem constants
#define T_TOKN 16
#define NUNITS 4096
#define LPATH  32
#define NPATHS 1024
#define BNUM   8

typedef __attribute__((ext_vector_type(8))) short short8;   // 8 bf16 in 4 VGPRs
typedef __attribute__((ext_vector_type(4))) short short4x;  // 4 bf16 in 2 VGPRs
typedef __attribute__((ext_vector_type(4))) float f32x4;    // MFMA accumulator

// ws float offsets
enum : size_t {
  OFF_WFRAG   = 0,                        // 524288 ushort: lstm W frags [tf|tb|pf|pb]
  OFF_LINFRAG = 262144,                   // 65536 ushort: lin/ul B-frags
  OFF_OUTF    = 294912,                   // token fwd h, bf16 16x4096x128
  OFF_OUTB    = OFF_OUTF + 4194304,       // token bwd h (time-realigned), bf16
  OFF_OUTLIN  = OFF_OUTB + 4194304,       // bf16 16x4096x128 (intermediate only)
  OFF_SCORES  = OFF_OUTLIN + 8388608,     // f32 16x4096
  OFF_TOKFEAT = OFF_SCORES + 65536,       // f32 4096x128
  OFF_POUTF   = OFF_TOKFEAT + 524288,     // path fwd h, bf16 32x1024x128
  OFF_POUTB   = OFF_POUTF + 2097152,
  OFF_INT     = OFF_POUTB + 2097152,      // ints: tok_len 4096 | fe 1024 | p_len 1024 |
                                          //       off_p 1024 | un_p 1024 | uorder 4096 | porder 1024
  WS_FLOATS   = OFF_INT + 16384
};

static __device__ __forceinline__ unsigned short f2bf(float f) {
  union { float f; unsigned u; } v; v.f = f;
  unsigned r = v.u + 0x7fffu + ((v.u >> 16) & 1u);
  return (unsigned short)(r >> 16);
}
static __device__ __forceinline__ float bf2f(unsigned short u) {
  union { unsigned u; float f; } v; v.u = ((unsigned)u) << 16;
  return v.f;
}
static __device__ __forceinline__ unsigned pack_bf(float a, float b) {
  return (unsigned)f2bf(a) | ((unsigned)f2bf(b) << 16);
}
static __device__ __forceinline__ float sigf(float x)      { return 1.f / (1.f + __expf(-x)); }
static __device__ __forceinline__ float tanhfast(float x)  { return 2.f / (1.f + __expf(-2.f * x)) - 1.f; }

// ---------------------------------------------------------------------------
// prep (coalesced, r6): thread = 8 consecutive k of one W row.
// Output bit layout identical to r0/r5 consumers.
// ---------------------------------------------------------------------------
__global__ void prep_kernel(
    const float* __restrict__ tWif, const float* __restrict__ tWhf,
    const float* __restrict__ tWib, const float* __restrict__ tWhb,
    const float* __restrict__ pWif, const float* __restrict__ pWhf,
    const float* __restrict__ pWib, const float* __restrict__ pWhb,
    const float* __restrict__ linW, const float* __restrict__ ulW,
    const int* __restrict__ units, const int* __restrict__ paths,
    const int* __restrict__ upd, const int* __restrict__ ppd,
    float* __restrict__ ws, int* __restrict__ ip)
{
  int idx = blockIdx.x * 256 + threadIdx.x;
  if (idx < 65536) {
    unsigned short* wf = (unsigned short*)(ws + OFF_WFRAG);
    int k8 = idx & 31, g = (idx >> 5) & 511, mat = idx >> 14;
    const float* Wi; const float* Wh;
    switch (mat) {
      case 0: Wi = tWif; Wh = tWhf; break;
      case 1: Wi = tWib; Wh = tWhb; break;
      case 2: Wi = pWif; Wh = pWhf; break;
      default: Wi = pWib; Wh = pWhb; break;
    }
    int kb = k8 << 3;
    const float* sp = (kb < 128) ? (Wi + g * 128 + kb) : (Wh + g * 128 + (kb - 128));
    float4 a = *(const float4*)sp;
    float4 b = *(const float4*)(sp + 4);
    int wvp = g >> 6, ct = (g >> 4) & 3, cl = g & 15;
    int ks = k8 >> 2, quad = k8 & 3;
    size_t base = ((size_t)mat << 17) +
                  (size_t)(((((wvp * 8 + ks) * 4 + ct) * 64) + quad * 16 + cl) << 3);
    short8 o;
    o[0] = (short)f2bf(a.x); o[1] = (short)f2bf(a.y);
    o[2] = (short)f2bf(a.z); o[3] = (short)f2bf(a.w);
    o[4] = (short)f2bf(b.x); o[5] = (short)f2bf(b.y);
    o[6] = (short)f2bf(b.z); o[7] = (short)f2bf(b.w);
    *(short8*)&wf[base] = o;
  } else if (idx < 65536 + 8192) {
    unsigned short* lf = (unsigned short*)(ws + OFF_LINFRAG);
    int j = idx - 65536;
    int k8 = j & 31, e = (j >> 5) & 127, mat = j >> 12;
    const float* W = mat ? ulW : linW;
    int kb = k8 << 3;
    const float* sp = W + e * 256 + kb;
    float4 a = *(const float4*)sp;
    float4 b = *(const float4*)(sp + 4);
    int ct = e >> 4, cl = e & 15;
    int ks = k8 >> 2, quad = k8 & 3;
    size_t base = ((size_t)mat << 15) +
                  (size_t)((((ct * 8 + ks) * 64) + quad * 16 + cl) << 3);
    short8 o;
    o[0] = (short)f2bf(a.x); o[1] = (short)f2bf(a.y);
    o[2] = (short)f2bf(a.z); o[3] = (short)f2bf(a.w);
    o[4] = (short)f2bf(b.x); o[5] = (short)f2bf(b.y);
    o[6] = (short)f2bf(b.z); o[7] = (short)f2bf(b.w);
    *(short8*)&lf[base] = o;
  } else if (idx < 73728 + 4096) {
    int n = idx - 73728;
    int len = T_TOKN;
    for (int t = 0; t < T_TOKN; ++t)
      if (units[t * NUNITS + n] == 0) { len = t; break; }
    ip[n] = len;                                   // tok_len
  } else if (idx < 77824 + 1024) {
    int p = idx - 77824;
    int* fe_a  = ip + 4096;
    int* p_len = ip + 5120;
    int* off_p = ip + 6144;
    int* un_p  = ip + 7168;
    int cum = 0; int d = BNUM - 1;
    for (int dd = 0; dd < BNUM; ++dd) {
      int c2 = cum + ppd[dd];
      if (p < c2) { d = dd; break; }
      cum = c2;
    }
    int off = 0;
    for (int dd = 0; dd < d; ++dd) off += upd[dd];
    int un = upd[d];
    off_p[p] = off; un_p[p] = un;
    int f = LPATH;
    for (int t = 0; t < LPATH; ++t)
      if (paths[t * NPATHS + p] == -1) { f = t; break; }
    fe_a[p] = f;
    int pl = LPATH;
    for (int t = 0; t < LPATH; ++t) {
      int v = paths[t * NPATHS + p];
      if ((t >= f) || (v < 0) || (v > un)) { pl = t; break; }
    }
    p_len[p] = pl;
  }
}

// ---------------------------------------------------------------------------
// Counting sort by length, DESCENDING (block 0: units by tok_len;
// block 1: paths by p_len). Any within-bucket order is correct: outputs are
// written at original positions and rows are independent, so any permutation
// is bit-exact. Descending order lets a block read its max len as element 0.
// ---------------------------------------------------------------------------
__global__ __launch_bounds__(1024) void sort_kernel(
    const int* __restrict__ ip, int* __restrict__ uorder, int* __restrict__ porder)
{
  __shared__ int cnt[33], base_[33];
  int tid = threadIdx.x;
  if (blockIdx.x == 0) {
    if (tid < 33) cnt[tid] = 0;
    __syncthreads();
    for (int n = tid; n < NUNITS; n += 1024)
      atomicAdd(&cnt[T_TOKN - ip[n]], 1);          // bucket 0 = longest
    __syncthreads();
    if (tid == 0) {
      int s = 0;
      for (int b = 0; b < 33; ++b) { base_[b] = s; s += cnt[b]; cnt[b] = 0; }
    }
    __syncthreads();
    for (int n = tid; n < NUNITS; n += 1024) {
      int b = T_TOKN - ip[n];
      int pos = base_[b] + atomicAdd(&cnt[b], 1);
      uorder[pos] = n;
    }
  } else {
    const int* pl = ip + 5120;
    if (tid < 33) cnt[tid] = 0;
    __syncthreads();
    for (int p = tid; p < NPATHS; p += 1024)
      atomicAdd(&cnt[LPATH - pl[p]], 1);
    __syncthreads();
    if (tid == 0) {
      int s = 0;
      for (int b = 0; b < 33; ++b) { base_[b] = s; s += cnt[b]; cnt[b] = 0; }
    }
    __syncthreads();
    for (int p = tid; p < NPATHS; p += 1024) {
      int b = LPATH - pl[p];
      int pos = base_[b] + atomicAdd(&cnt[b], 1);
      porder[pos] = p;
    }
  }
}

// ---------------------------------------------------------------------------
// MFMA BiLSTM, 16-wave blocks, resident B (32 gate-cols/wave, 64 VGPR/lane).
// Round-7: 2-RESIDENT blocks + length-sorted work elimination.
//  * MR=16 tile, M=16 (MODE0) / M=4 (MODE1), grid (256,2) = 512 blocks ->
//    2 blocks co-resident per CU (LDS ~42KB, 32 waves): cross-block overlap
//    fills the barrier stalls one lockstep block can't hide (r0-r6 all hit
//    the same ~5us/step floor at 1 block/CU).
//  * Blocks take units/paths via DESC-sorted order[]; run only TT_run =
//    len(order[n0]) steps (= block max). dir=1 uses reversed rank so a CU
//    pairs a long block with a short one (balanced makespan).
//  * NO dead-step stores at all: gemm<1> now masks rows t>=len (same as
//    gemm<0>), producing identical bias rows downstream.
// Keeps: r5 gates layout (gates[u][g], b64 PW reads, 4B stores), idxL
// preload, r0 phase order, bf16 OUTLIN.
// ---------------------------------------------------------------------------
template <int MODE>
__global__ __launch_bounds__(1024, 4) void lstm_kernel(
    const unsigned short* __restrict__ wfragAll,
    const float* __restrict__ biasF, const float* __restrict__ biasB,
    const float* __restrict__ src,       // emb or tok_feat (f32)
    const int* __restrict__ idxsrc,      // units or paths
    const int* __restrict__ lens,        // tok_len or p_len
    const int* __restrict__ order,       // uorder or porder (desc by len)
    const int* __restrict__ fe_a, const int* __restrict__ off_p, const int* __restrict__ un_p,
    unsigned short* __restrict__ outF, unsigned short* __restrict__ outB)
{
  constexpr int NN   = MODE ? NPATHS : NUNITS;
  constexpr int TT   = MODE ? LPATH : T_TOKN;
  constexpr int M    = MODE ? 4 : 16;     // real sequences per block
  constexpr int ASTR = 264;               // A-tile row stride (ushorts)
  constexpr int GSTR = 514;               // gates row stride (f32)

  __shared__ unsigned short ash[16 * ASTR];  // [u][0:128)=x  [u][128:256)=h
  __shared__ float gates[16 * GSTR];
  __shared__ int   idxL[M * TT];             // preloaded index columns

  int tid  = threadIdx.x;
  int dir  = blockIdx.y;
  // balanced pairing: dir1 takes reversed rank so co-resident pairs mix
  // long+short blocks
  int rank = dir ? ((int)gridDim.x - 1 - (int)blockIdx.x) : (int)blockIdx.x;
  int n0   = rank * M;
  int lane = tid & 63, wv = tid >> 6;       // wv in [0,16)
  int cl   = lane & 15, quad = lane >> 4;

  // ---- resident B fragments: wave wv covers gates [wv*32, wv*32+32) ----
  const unsigned short* wbase =
      wfragAll + (size_t)((MODE ? 2 : 0) + dir) * 131072;
  int wv8 = wv >> 1;
  short8 bfr[8][2];
#pragma unroll
  for (int ks = 0; ks < 8; ++ks)
#pragma unroll
    for (int c2 = 0; c2 < 2; ++c2) {
      int ct = ((wv & 1) << 1) | c2;
      bfr[ks][c2] = *(const short8*)&wbase[((((wv8 * 8 + ks) * 4 + ct) * 64) + lane) * 8];
    }

  // ---- zero LDS A-tile (MODE1: whole tile incl dummy rows) ----
  if (MODE == 0) {
    for (int i = tid; i < 16 * 128; i += 1024)
      ash[(i >> 7) * ASTR + 128 + (i & 127)] = 0;
  } else {
    for (int i = tid; i < 16 * ASTR; i += 1024) ash[i] = 0;
  }
  // ---- preload idx columns (through the permutation) ----
  for (int i = tid; i < M * TT; i += 1024) {
    int u = i / TT, tt = i - u * TT;
    idxL[i] = idxsrc[tt * NN + order[n0 + u]];
  }

  const int TT_run = lens[order[n0]];   // desc sort -> element 0 is block max

  // ---- pointwise thread state ----
  const float* bcp = dir ? biasB : biasF;
  // MODE0: thread = 1 unit x 2 cols.  MODE1: 1 unit x 1 col (ug<4 active).
  int j2 = MODE ? (tid & 127) : ((tid & 63) * 2);
  int ug = MODE ? (tid >> 7)  : (tid >> 6);
  bool pw_act = MODE ? (ug < M) : true;
  float2 b2[4];
#pragma unroll
  for (int q = 0; q < 4; ++q) {
    if (MODE == 0) b2[q] = *(const float2*)&bcp[q * 128 + j2];
    else           b2[q] = make_float2(bcp[q * 128 + j2], 0.f);
  }
  int pun = order[n0 + (pw_act ? ug : 0)];   // this thread's sequence (global id)
  int pL  = lens[pun];
  float cstA = 0.f, cstB = 0.f;

  // ---- gather thread state ----
  int gu, gk0;
  if (MODE == 0) { gu = tid >> 6; gk0 = (tid & 63) * 2; }   // 16 rows x 64 thr x f32x2
  else           { gu = tid >> 7; gk0 = tid & 127; }        // rows x 128 thr x f32
  bool g_act = MODE ? (gu < M) : true;
  int gn = order[n0 + (g_act ? gu : 0)];
  int glen = lens[gn];
  int gfe = 0, goff = 0, gun = 0;
  if (MODE) { gfe = fe_a[gn]; goff = off_p[gn]; gun = un_p[gn]; }

  float2 xq; float xs;
  __syncthreads();   // zeros + idxL visible

  // ---- preamble: load + write x(0) ----
  if (g_act) {
    int tau = dir ? min(max(glen - 1, 0), TT - 1) : 0;
    int v = idxL[gu * TT + tau];
    if (MODE == 0) {
      xq = *(const float2*)&src[(size_t)v * 128 + gk0];
      *(unsigned*)&ash[gu * ASTR + gk0] = pack_bf(xq.x, xq.y);
    } else {
      bool keep = (tau < gfe) && (v >= 0) && (v < gun);
      xs = keep ? src[(size_t)min(v + goff, NUNITS - 1) * 128 + gk0] : 0.f;
      ash[gu * ASTR + gk0] = f2bf(xs);
    }
  }
  __syncthreads();   // x(0) visible

#pragma unroll 1
  for (int t = 0; t < TT_run; ++t) {
    // ===== MFMA phase =====
    {
      int tn = (t + 1 < TT_run) ? t + 1 : t;
      int taun = dir ? min(max(glen - 1 - tn, 0), TT - 1) : tn;
      int vn = g_act ? idxL[gu * TT + taun] : 0;
      f32x4 acc0 = {0.f, 0.f, 0.f, 0.f}, acc1 = {0.f, 0.f, 0.f, 0.f};
#pragma unroll
      for (int ks = 0; ks < 8; ++ks) {
        short8 afr = *(const short8*)&ash[cl * ASTR + ks * 32 + (quad << 3)];
        acc0 = __builtin_amdgcn_mfma_f32_16x16x32_bf16(afr, bfr[ks][0], acc0, 0, 0, 0);
        acc1 = __builtin_amdgcn_mfma_f32_16x16x32_bf16(afr, bfr[ks][1], acc1, 0, 0, 0);
      }
      // dependent x(t+1) load — latency overlaps gates-write + barrier
      if (g_act) {
        if (MODE == 0) {
          xq = *(const float2*)&src[(size_t)vn * 128 + gk0];
        } else {
          bool keep = (taun < gfe) && (vn >= 0) && (vn < gun);
          xs = keep ? src[(size_t)min(vn + goff, NUNITS - 1) * 128 + gk0] : 0.f;
        }
      }
      // preacts -> LDS gates (C-layout: col=lane&15, row=quad*4+reg)
      {
        int g = wv * 32 + cl;
        int ub = quad << 2;
#pragma unroll
        for (int r = 0; r < 4; ++r) {
          gates[(ub + r) * GSTR + g]      = acc0[r];
          gates[(ub + r) * GSTR + g + 16] = acc1[r];
        }
      }
    }
    __syncthreads();   // gates ready; A-tile reads done

    // ===== PW phase (no dead stores: rows t>=len are never read downstream)
    if (pw_act && t < pL) {
      if (MODE == 0) {
        const float* gg = gates + ug * GSTR + j2;
        float2 g0 = *(const float2*)(gg);
        float2 g1 = *(const float2*)(gg + 128);
        float2 g2 = *(const float2*)(gg + 256);
        float2 g3 = *(const float2*)(gg + 384);
        float i0 = sigf(g0.x + b2[0].x), i1 = sigf(g0.y + b2[0].y);
        float f0 = sigf(g1.x + b2[1].x), f1 = sigf(g1.y + b2[1].y);
        float c0 = tanhfast(g2.x + b2[2].x), c1 = tanhfast(g2.y + b2[2].y);
        float o0 = sigf(g3.x + b2[3].x), o1 = sigf(g3.y + b2[3].y);
        float cA = f0 * cstA + i0 * c0;
        float cB = f1 * cstB + i1 * c1;
        cstA = cA; cstB = cB;
        unsigned hp = pack_bf(o0 * tanhfast(cA), o1 * tanhfast(cB));
        *(unsigned*)&ash[ug * ASTR + 128 + j2] = hp;
        if (dir == 0) *(unsigned*)&outF[((size_t)t * NN + pun) * 128 + j2] = hp;
        else          *(unsigned*)&outB[((size_t)(pL - 1 - t) * NN + pun) * 128 + j2] = hp;
      } else {
        const float* gg = gates + ug * GSTR + j2;
        float p0 = gg[0]   + b2[0].x;
        float p1 = gg[128] + b2[1].x;
        float p2 = gg[256] + b2[2].x;
        float p3 = gg[384] + b2[3].x;
        float ig = sigf(p0), fg = sigf(p1), gg2 = tanhfast(p2), og = sigf(p3);
        float c = fg * cstA + ig * gg2;
        cstA = c;
        unsigned short hb = f2bf(og * tanhfast(c));
        ash[ug * ASTR + 128 + j2] = hb;
        if (dir == 0) outF[((size_t)t * NN + pun) * 128 + j2] = hb;
        else          outB[((size_t)(pL - 1 - t) * NN + pun) * 128 + j2] = hb;
      }
    }
    // x(t+1) into A-tile (prefetched during MFMA phase)
    if (g_act && t + 1 < TT_run) {
      if (MODE == 0) *(unsigned*)&ash[gu * ASTR + gk0] = pack_bf(xq.x, xq.y);
      else           ash[gu * ASTR + gk0] = f2bf(xs);
    }
    __syncthreads();   // h(t) + x(t+1) visible
  }
}

// ---------------------------------------------------------------------------
// MFMA GEMM: rows x 128, K=256, A = bf16 [INf|INb] from global, B resident.
// BOTH epilogues now mask rows t >= lens[n] (A-frag zero -> OUT = bias).
// EPI 0: f32 store (final output).  EPI 1: bf16 OUT + fused LN/tanh/attn.
// ---------------------------------------------------------------------------
template <int EPI>
__global__ __launch_bounds__(256) void gemm_mfma(
    const unsigned short* __restrict__ INf, const unsigned short* __restrict__ INb,
    const int* __restrict__ lens,
    const unsigned short* __restrict__ Bfrag, const float* __restrict__ bias,
    void* __restrict__ OUTv, float* __restrict__ scores,
    const float* __restrict__ lng, const float* __restrict__ lnb,
    const float* __restrict__ attw, const float* __restrict__ attb,
    const int* __restrict__ units, int Nn)
{
  constexpr int OSTR = 132;
  __shared__ float outs[64 * OSTR];
  __shared__ float red1[256];
  __shared__ float red2[256];
  __shared__ float rowm[64], rowr[64];
  __shared__ float awsh[128], lgsh[128], lbsh[128];

  int tid = threadIdx.x, lane = tid & 63, wv = tid >> 6;
  int row0 = blockIdx.x * 64;
  int t = row0 / Nn, n0 = row0 % Nn;   // 64-row blocks never straddle t

  if (EPI == 1 && tid < 128) {
    awsh[tid] = attw[tid]; lgsh[tid] = lng[tid]; lbsh[tid] = lnb[tid];
  }

  short8 bfr[8][2];
#pragma unroll
  for (int ks = 0; ks < 8; ++ks)
#pragma unroll
    for (int c2 = 0; c2 < 2; ++c2) {
      int ct = wv * 2 + c2;
      bfr[ks][c2] = *(const short8*)&Bfrag[(((ct * 8 + ks) * 64) + lane) * 8];
    }

  int rb = lane & 15;
  int koq = (lane >> 4) << 3;
  bool val[4];
#pragma unroll
  for (int rt = 0; rt < 4; ++rt)
    val[rt] = (t < lens[n0 + rt * 16 + rb]);

  f32x4 acc[4][2];
#pragma unroll
  for (int rt = 0; rt < 4; ++rt)
#pragma unroll
    for (int c2 = 0; c2 < 2; ++c2) {
      f32x4 z = {0.f, 0.f, 0.f, 0.f};
      acc[rt][c2] = z;
    }

#pragma unroll
  for (int ks = 0; ks < 8; ++ks) {
    const unsigned short* P = (ks < 4) ? INf : INb;
    int koff = (ks & 3) * 32 + koq;
#pragma unroll
    for (int rt = 0; rt < 4; ++rt) {
      short8 a = {0, 0, 0, 0, 0, 0, 0, 0};
      if (val[rt])
        a = *(const short8*)&P[((size_t)(row0 + rt * 16 + rb)) * 128 + koff];
#pragma unroll
      for (int c2 = 0; c2 < 2; ++c2)
        acc[rt][c2] = __builtin_amdgcn_mfma_f32_16x16x32_bf16(
            a, bfr[ks][c2], acc[rt][c2], 0, 0, 0);
    }
  }

  float bc[2];
#pragma unroll
  for (int c2 = 0; c2 < 2; ++c2) bc[c2] = bias[wv * 32 + c2 * 16 + rb];
#pragma unroll
  for (int rt = 0; rt < 4; ++rt)
#pragma unroll
    for (int c2 = 0; c2 < 2; ++c2) {
      int col = wv * 32 + c2 * 16 + rb;
      int ub  = rt * 16 + ((lane >> 4) << 2);
#pragma unroll
      for (int r = 0; r < 4; ++r)
        outs[(ub + r) * OSTR + col] = acc[rt][c2][r] + bc[c2];
    }
  __syncthreads();

  int row = tid >> 2, seg = tid & 3;
  const float* rp = &outs[row * OSTR + seg * 32];
  size_t go = ((size_t)(row0 + row)) * 128 + seg * 32;

  if (EPI == 0) {
    float* OUT = (float*)OUTv;
#pragma unroll
    for (int x = 0; x < 8; ++x)
      *(f32x4*)&OUT[go + x * 4] = *(const f32x4*)&rp[x * 4];
  } else {
    unsigned short* OUT = (unsigned short*)OUTv;
    f32x4 v[8];
    float s = 0.f, s2 = 0.f;
#pragma unroll
    for (int x = 0; x < 8; ++x) {
      v[x] = *(const f32x4*)&rp[x * 4];
#pragma unroll
      for (int c = 0; c < 4; ++c) { s += v[x][c]; s2 += v[x][c] * v[x][c]; }
    }
    red1[tid] = s; red2[tid] = s2;
    __syncthreads();
    if (tid < 64) {
      float a = red1[tid * 4] + red1[tid * 4 + 1] + red1[tid * 4 + 2] + red1[tid * 4 + 3];
      float b = red2[tid * 4] + red2[tid * 4 + 1] + red2[tid * 4 + 2] + red2[tid * 4 + 3];
      float m = a * (1.f / 128.f);
      float var = b * (1.f / 128.f) - m * m;
      rowm[tid] = m;
      rowr[tid] = rsqrtf(var + 1e-5f);
    }
    __syncthreads();
    float m = rowm[row], rs = rowr[row];
    float sp = 0.f;
#pragma unroll
    for (int x = 0; x < 8; ++x) {
      short4x pv;
#pragma unroll
      for (int c = 0; c < 4; ++c) {
        int col = seg * 32 + x * 4 + c;
        float q = tanhfast((v[x][c] - m) * rs * lgsh[col] + lbsh[col]);
        sp += q * awsh[col];
        pv[c] = (short)f2bf(v[x][c]);
      }
      *(short4x*)&OUT[go + x * 4] = pv;   // bf16 intermediate (8B store)
    }
    red1[tid] = sp;
    __syncthreads();
    if (tid < 64) {
      float s3 = red1[tid * 4] + red1[tid * 4 + 1] + red1[tid * 4 + 2] + red1[tid * 4 + 3]
               + attb[0];
      int n = n0 + tid;
      if (units[t * NUNITS + n] == 0) s3 = -1e9f;
      scores[t * NUNITS + n] = s3;
    }
  }
}

// ---------------------------------------------------------------------------
// Softmax over T=16 + attention-weighted pooling -> tok_feat[n][e]
// ---------------------------------------------------------------------------
__global__ __launch_bounds__(128) void softmax_feat_kernel(
    const float* __restrict__ scores, const unsigned short* __restrict__ out_lin,
    float* __restrict__ tok_feat)
{
  int n = blockIdx.x;
  int e = threadIdx.x;
  float s[T_TOKN];
  float m = -1e30f;
#pragma unroll
  for (int t = 0; t < T_TOKN; ++t) { s[t] = scores[t * NUNITS + n]; m = fmaxf(m, s[t]); }
  float sum = 0.f;
#pragma unroll
  for (int t = 0; t < T_TOKN; ++t) { s[t] = expf(s[t] - m); sum += s[t]; }
  float inv = 1.f / sum;
  float a = 0.f;
#pragma unroll
  for (int t = 0; t < T_TOKN; ++t)
    a += s[t] * inv * bf2f(out_lin[((size_t)t * NUNITS + n) * 128 + e]);
  tok_feat[n * 128 + e] = a;
}

// ---------------------------------------------------------------------------
extern "C" void kernel_launch(void* const* d_in, const int* in_sizes, int n_in,
                              void* d_out, int out_size, void* d_ws, size_t ws_size,
                              hipStream_t stream)
{
  const int*   units = (const int*)d_in[0];
  const int*   paths = (const int*)d_in[1];
  const int*   upd   = (const int*)d_in[2];
  const int*   ppd   = (const int*)d_in[3];
  const float* emb   = (const float*)d_in[4];
  const float* tWif  = (const float*)d_in[5];
  const float* tWhf  = (const float*)d_in[6];
  const float* tbf   = (const float*)d_in[7];
  const float* tWib  = (const float*)d_in[8];
  const float* tWhb  = (const float*)d_in[9];
  const float* tbb   = (const float*)d_in[10];
  const float* linW  = (const float*)d_in[11];
  const float* linb  = (const float*)d_in[12];
  const float* lng   = (const float*)d_in[13];
  const float* lnb   = (const float*)d_in[14];
  const float* attw  = (const float*)d_in[15];
  const float* attb  = (const float*)d_in[16];
  const float* pWif  = (const float*)d_in[17];
  const float* pWhf  = (const float*)d_in[18];
  const float* pbf   = (const float*)d_in[19];
  const float* pWib  = (const float*)d_in[20];
  const float* pWhb  = (const float*)d_in[21];
  const float* pbb   = (const float*)d_in[22];
  const float* ulW   = (const float*)d_in[23];
  const float* ulb   = (const float*)d_in[24];

  float* ws = (float*)d_ws;
  int*   ip = (int*)(ws + OFF_INT);
  if (ws_size < WS_FLOATS * sizeof(float)) return;

  unsigned short* wfrag   = (unsigned short*)(ws + OFF_WFRAG);
  unsigned short* linfrag = (unsigned short*)(ws + OFF_LINFRAG);
  unsigned short* ulfrag  = linfrag + 32768;
  unsigned short* OUTF  = (unsigned short*)(ws + OFF_OUTF);
  unsigned short* OUTB  = (unsigned short*)(ws + OFF_OUTB);
  unsigned short* POUTF = (unsigned short*)(ws + OFF_POUTF);
  unsigned short* POUTB = (unsigned short*)(ws + OFF_POUTB);
  int* uorder = ip + 8192;
  int* porder = ip + 12288;

  prep_kernel<<<308, 256, 0, stream>>>(tWif, tWhf, tWib, tWhb,
                                       pWif, pWhf, pWib, pWhb,
                                       linW, ulW, units, paths, upd, ppd,
                                       ws, ip);

  sort_kernel<<<2, 1024, 0, stream>>>(ip, uorder, porder);

  lstm_kernel<0><<<dim3(256, 2), 1024, 0, stream>>>(
      wfrag, tbf, tbb, emb, units, ip /*tok_len*/, uorder,
      nullptr, nullptr, nullptr, OUTF, OUTB);

  gemm_mfma<1><<<1024, 256, 0, stream>>>(
      OUTF, OUTB, ip /*tok_len*/, linfrag, linb,
      (void*)(ws + OFF_OUTLIN), ws + OFF_SCORES, lng, lnb, attw, attb, units, NUNITS);

  softmax_feat_kernel<<<4096, 128, 0, stream>>>(
      ws + OFF_SCORES, (const unsigned short*)(ws + OFF_OUTLIN),
      ws + OFF_TOKFEAT);

  lstm_kernel<1><<<dim3(256, 2), 1024, 0, stream>>>(
      wfrag, pbf, pbb, ws + OFF_TOKFEAT, paths, ip + 5120 /*p_len*/, porder,
      ip + 4096 /*fe*/, ip + 6144 /*off_p*/, ip + 7168 /*un_p*/,
      POUTF, POUTB);

  gemm_mfma<0><<<512, 256, 0, stream>>>(
      POUTF, POUTB, ip + 5120 /*p_len*/, ulfrag, ulb,
      (void*)d_out, nullptr, nullptr, nullptr, nullptr, nullptr, nullptr, NPATHS);
}

// Round 8
// 303.296 us; speedup vs baseline: 1.1552x; 1.1552x over previous
//
#include <hip/hip_runtime.h>
#include <cstdint>
#include <cstddef>

// Problem constants
#define T_TOKN 16
#define NUNITS 4096
#define LPATH  32
#define NPATHS 1024
#define BNUM   8

typedef __attribute__((ext_vector_type(8))) short short8;   // 8 bf16 in 4 VGPRs
typedef __attribute__((ext_vector_type(4))) short short4x;  // 4 bf16 in 2 VGPRs
typedef __attribute__((ext_vector_type(4))) float f32x4;    // MFMA accumulator

// ws float offsets
enum : size_t {
  OFF_WFRAG   = 0,                        // 524288 ushort: lstm W frags [tf|tb|pf|pb]
  OFF_LINFRAG = 262144,                   // 65536 ushort: lin/ul B-frags
  OFF_OUTF    = 294912,                   // token fwd h, bf16 16x4096x128
  OFF_OUTB    = OFF_OUTF + 4194304,       // token bwd h (time-realigned), bf16
  OFF_OUTLIN  = OFF_OUTB + 4194304,       // bf16 16x4096x128 (intermediate only)
  OFF_SCORES  = OFF_OUTLIN + 8388608,     // f32 16x4096
  OFF_TOKFEAT = OFF_SCORES + 65536,       // bf16 4096x128 (intermediate only)
  OFF_POUTF   = OFF_TOKFEAT + 524288,     // path fwd h, bf16 32x1024x128
  OFF_POUTB   = OFF_POUTF + 2097152,
  OFF_INT     = OFF_POUTB + 2097152,      // ints: tok_len 4096 | fe 1024 | p_len 1024 | off_p 1024 | un_p 1024
  WS_FLOATS   = OFF_INT + 8192
};

static __device__ __forceinline__ unsigned short f2bf(float f) {
  union { float f; unsigned u; } v; v.f = f;
  unsigned r = v.u + 0x7fffu + ((v.u >> 16) & 1u);
  return (unsigned short)(r >> 16);
}
static __device__ __forceinline__ float bf2f(unsigned short u) {
  union { unsigned u; float f; } v; v.u = ((unsigned)u) << 16;
  return v.f;
}
static __device__ __forceinline__ unsigned pack_bf(float a, float b) {
  return (unsigned)f2bf(a) | ((unsigned)f2bf(b) << 16);
}
static __device__ __forceinline__ float sigf(float x)      { return 1.f / (1.f + __expf(-x)); }
static __device__ __forceinline__ float tanhfast(float x)  { return 2.f / (1.f + __expf(-2.f * x)) - 1.f; }

// ---------------------------------------------------------------------------
// prep (coalesced, r6-verified): thread = 8 consecutive k of one W row ->
// float4 x2 coalesced reads, aligned 16B short8 writes. Output bit layout
// identical to the r0/r5 consumers.
// ---------------------------------------------------------------------------
__global__ void prep_kernel(
    const float* __restrict__ tWif, const float* __restrict__ tWhf,
    const float* __restrict__ tWib, const float* __restrict__ tWhb,
    const float* __restrict__ pWif, const float* __restrict__ pWhf,
    const float* __restrict__ pWib, const float* __restrict__ pWhb,
    const float* __restrict__ linW, const float* __restrict__ ulW,
    const int* __restrict__ units, const int* __restrict__ paths,
    const int* __restrict__ upd, const int* __restrict__ ppd,
    float* __restrict__ ws, int* __restrict__ ip)
{
  int idx = blockIdx.x * 256 + threadIdx.x;
  if (idx < 65536) {
    unsigned short* wf = (unsigned short*)(ws + OFF_WFRAG);
    int k8 = idx & 31, g = (idx >> 5) & 511, mat = idx >> 14;
    const float* Wi; const float* Wh;
    switch (mat) {
      case 0: Wi = tWif; Wh = tWhf; break;
      case 1: Wi = tWib; Wh = tWhb; break;
      case 2: Wi = pWif; Wh = pWhf; break;
      default: Wi = pWib; Wh = pWhb; break;
    }
    int kb = k8 << 3;
    const float* sp = (kb < 128) ? (Wi + g * 128 + kb) : (Wh + g * 128 + (kb - 128));
    float4 a = *(const float4*)sp;
    float4 b = *(const float4*)(sp + 4);
    int wvp = g >> 6, ct = (g >> 4) & 3, cl = g & 15;
    int ks = k8 >> 2, quad = k8 & 3;
    size_t base = ((size_t)mat << 17) +
                  (size_t)(((((wvp * 8 + ks) * 4 + ct) * 64) + quad * 16 + cl) << 3);
    short8 o;
    o[0] = (short)f2bf(a.x); o[1] = (short)f2bf(a.y);
    o[2] = (short)f2bf(a.z); o[3] = (short)f2bf(a.w);
    o[4] = (short)f2bf(b.x); o[5] = (short)f2bf(b.y);
    o[6] = (short)f2bf(b.z); o[7] = (short)f2bf(b.w);
    *(short8*)&wf[base] = o;
  } else if (idx < 65536 + 8192) {
    unsigned short* lf = (unsigned short*)(ws + OFF_LINFRAG);
    int j = idx - 65536;
    int k8 = j & 31, e = (j >> 5) & 127, mat = j >> 12;
    const float* W = mat ? ulW : linW;
    int kb = k8 << 3;
    const float* sp = W + e * 256 + kb;
    float4 a = *(const float4*)sp;
    float4 b = *(const float4*)(sp + 4);
    int ct = e >> 4, cl = e & 15;
    int ks = k8 >> 2, quad = k8 & 3;
    size_t base = ((size_t)mat << 15) +
                  (size_t)((((ct * 8 + ks) * 64) + quad * 16 + cl) << 3);
    short8 o;
    o[0] = (short)f2bf(a.x); o[1] = (short)f2bf(a.y);
    o[2] = (short)f2bf(a.z); o[3] = (short)f2bf(a.w);
    o[4] = (short)f2bf(b.x); o[5] = (short)f2bf(b.y);
    o[6] = (short)f2bf(b.z); o[7] = (short)f2bf(b.w);
    *(short8*)&lf[base] = o;
  } else if (idx < 73728 + 4096) {
    int n = idx - 73728;
    int len = T_TOKN;
    for (int t = 0; t < T_TOKN; ++t)
      if (units[t * NUNITS + n] == 0) { len = t; break; }
    ip[n] = len;                                   // tok_len
  } else if (idx < 77824 + 1024) {
    int p = idx - 77824;
    int* fe_a  = ip + 4096;
    int* p_len = ip + 5120;
    int* off_p = ip + 6144;
    int* un_p  = ip + 7168;
    int cum = 0; int d = BNUM - 1;
    for (int dd = 0; dd < BNUM; ++dd) {
      int c2 = cum + ppd[dd];
      if (p < c2) { d = dd; break; }
      cum = c2;
    }
    int off = 0;
    for (int dd = 0; dd < d; ++dd) off += upd[dd];
    int un = upd[d];
    off_p[p] = off; un_p[p] = un;
    int f = LPATH;
    for (int t = 0; t < LPATH; ++t)
      if (paths[t * NPATHS + p] == -1) { f = t; break; }
    fe_a[p] = f;
    int pl = LPATH;
    for (int t = 0; t < LPATH; ++t) {
      int v = paths[t * NPATHS + p];
      if ((t >= f) || (v < 0) || (v > un)) { pl = t; break; }
    }
    p_len[p] = pl;
  }
}

// ---------------------------------------------------------------------------
// MFMA BiLSTM, 16-wave blocks, resident B (32 gate-cols/wave, 64 VGPR/lane).
// Round-8 = exact r5 structure (best: lstm0 = 81us) + safe deltas:
//  * NO dead-step stores at all (both GEMMs now mask rows t >= len, so
//    those OUT rows are never read; r7-verified numerically).
//  * MODE 1 x-source (tok_feat) is bf16: gather loads are ushort — halves
//    the scattered-gather traffic; bit-exact (value was rounded to bf16 at
//    LDS write anyway).
// Keeps: idxL preload, wave-uniform dead-step transcendental skip, r0 phase
// order, gates[u][g] layout, bf16 OUTLIN.
// MODE 0: token (emb gather f32, M=32, thread = 2 units x 2 cols).
// MODE 1: path (tok_feat bf16 gather w/ keep mask, M=8, scalar pointwise).
// ---------------------------------------------------------------------------
template <int MODE>
__global__ __launch_bounds__(1024, 4) void lstm_kernel(
    const unsigned short* __restrict__ wfragAll,
    const float* __restrict__ biasF, const float* __restrict__ biasB,
    const void* __restrict__ srcv,       // emb (f32) or tok_feat (bf16)
    const int* __restrict__ idxsrc,      // units or paths
    const int* __restrict__ lens,        // tok_len or p_len
    const int* __restrict__ fe_a, const int* __restrict__ off_p, const int* __restrict__ un_p,
    unsigned short* __restrict__ outF, unsigned short* __restrict__ outB)
{
  constexpr int NN   = MODE ? NPATHS : NUNITS;
  constexpr int TT   = MODE ? LPATH : T_TOKN;
  constexpr int M    = MODE ? 8 : 32;     // real sequences per block
  constexpr int MR   = MODE ? 16 : 32;    // MFMA tile rows
  constexpr int NRT  = MR / 16;
  constexpr int ASTR = 264;               // A-tile row stride (ushorts)
  constexpr int GSTR = 514;               // gates row stride (f32)

  __shared__ unsigned short ash[MR * ASTR];  // [u][0:128)=x  [u][128:256)=h
  __shared__ float gates[MR * GSTR];
  __shared__ int   idxL[M * TT];             // preloaded index columns

  const float* srcf = (const float*)srcv;                 // MODE 0
  const unsigned short* src16 = (const unsigned short*)srcv;  // MODE 1

  int tid  = threadIdx.x;
  int dir  = blockIdx.y;
  int n0   = blockIdx.x * M;
  int lane = tid & 63, wv = tid >> 6;       // wv in [0,16)

  // ---- resident B fragments: wave wv covers gates [wv*32, wv*32+32) ----
  const unsigned short* wbase =
      wfragAll + (size_t)((MODE ? 2 : 0) + dir) * 131072;
  int wv8 = wv >> 1;
  short8 bfr[8][2];
#pragma unroll
  for (int ks = 0; ks < 8; ++ks)
#pragma unroll
    for (int c2 = 0; c2 < 2; ++c2) {
      int ct = ((wv & 1) << 1) | c2;
      bfr[ks][c2] = *(const short8*)&wbase[((((wv8 * 8 + ks) * 4 + ct) * 64) + lane) * 8];
    }

  // ---- zero LDS (h region; MODE 1: whole tile incl dummy rows) ----
  if (MODE == 0) {
    for (int i = tid; i < MR * 128; i += 1024)
      ash[(i >> 7) * ASTR + 128 + (i & 127)] = 0;
  } else {
    for (int i = tid; i < MR * ASTR; i += 1024) ash[i] = 0;
  }
  // ---- preload idx columns: idxL[u*TT + t] = idxsrc[t*NN + n0+u] ----
  for (int i = tid; i < M * TT; i += 1024) {
    int u = i / TT, tt = i - u * TT;
    idxL[i] = idxsrc[tt * NN + (n0 + u)];
  }

  // ---- pointwise thread state ----
  const float* bcp = dir ? biasB : biasF;
  // MODE 0: thread = wave's unit pair x j pair.  MODE 1: 1 unit x 1 j.
  int j2 = MODE ? (tid & 127) : ((tid & 63) * 2);
  int ug = MODE ? (tid >> 7)  : (tid >> 6);
  float2 b2[4];
#pragma unroll
  for (int q = 0; q < 4; ++q) {
    if (MODE == 0) b2[q] = *(const float2*)&bcp[q * 128 + j2];
    else           b2[q] = make_float2(bcp[q * 128 + j2], 0.f);
  }
  constexpr int NU = MODE ? 1 : 2;          // units per pointwise thread
  float cst0[NU], cst1[NU];
  int   ulen[NU];
#pragma unroll
  for (int i = 0; i < NU; ++i) {
    cst0[i] = 0.f; cst1[i] = 0.f;
    ulen[i] = lens[n0 + ug * NU + i];
  }

  // ---- gather thread state ----
  int gu, gk0;
  if (MODE == 0) { gu = tid >> 5; gk0 = (tid & 31) * 4; }   // 32 rows x 32 thr
  else           { gu = tid >> 7; gk0 = tid & 127; }        // 8 rows x 128 thr
  int gn = n0 + gu;
  int glen = lens[gn];
  int gfe = 0, goff = 0, gun = 0;
  if (MODE) { gfe = fe_a[gn]; goff = off_p[gn]; gun = un_p[gn]; }

  float4 xq; unsigned short xs;
  __syncthreads();   // zeros + idxL visible

  // ---- preamble: load + write x(0) ----
  {
    int tau = dir ? min(max(glen - 1, 0), TT - 1) : 0;
    int v = idxL[gu * TT + tau];
    if (MODE == 0) {
      xq = *(const float4*)&srcf[(size_t)v * 128 + gk0];
    } else {
      bool keep = (tau < gfe) && (v >= 0) && (v < gun);
      xs = keep ? src16[(size_t)min(v + goff, NUNITS - 1) * 128 + gk0] : (unsigned short)0;
    }
  }
  if (MODE == 0) {
    short4x x4;
    x4[0] = (short)f2bf(xq.x); x4[1] = (short)f2bf(xq.y);
    x4[2] = (short)f2bf(xq.z); x4[3] = (short)f2bf(xq.w);
    *(short4x*)&ash[gu * ASTR + gk0] = x4;
  } else {
    ash[gu * ASTR + gk0] = xs;
  }
  __syncthreads();   // x(0) visible

#pragma unroll 1
  for (int t = 0; t < TT; ++t) {
    // ===== MFMA phase (r0 ordering) =====
    {
      int tn = (t + 1 < TT) ? t + 1 : t;
      int taun = dir ? min(max(glen - 1 - tn, 0), TT - 1) : tn;
      int vn = idxL[gu * TT + taun];     // LDS read; no global idx chain
      f32x4 acc[NRT][2];
#pragma unroll
      for (int rt = 0; rt < NRT; ++rt)
#pragma unroll
        for (int c2 = 0; c2 < 2; ++c2) {
          f32x4 z = {0.f, 0.f, 0.f, 0.f};
          acc[rt][c2] = z;
        }
#pragma unroll
      for (int ks = 0; ks < 8; ++ks) {
        short8 afr[NRT];
#pragma unroll
        for (int rt = 0; rt < NRT; ++rt)
          afr[rt] = *(const short8*)&ash[(rt * 16 + (lane & 15)) * ASTR + ks * 32 + ((lane >> 4) << 3)];
#pragma unroll
        for (int rt = 0; rt < NRT; ++rt)
#pragma unroll
          for (int c2 = 0; c2 < 2; ++c2)
            acc[rt][c2] = __builtin_amdgcn_mfma_f32_16x16x32_bf16(
                afr[rt], bfr[ks][c2], acc[rt][c2], 0, 0, 0);
      }
      // dependent x(t+1) load — latency overlaps gates-write + barrier
      if (MODE == 0) {
        xq = *(const float4*)&srcf[(size_t)vn * 128 + gk0];
      } else {
        bool keep = (taun < gfe) && (vn >= 0) && (vn < gun);
        xs = keep ? src16[(size_t)min(vn + goff, NUNITS - 1) * 128 + gk0] : (unsigned short)0;
      }
      // preacts -> LDS gates (C-layout: col=lane&15, row=quad*4+reg)
#pragma unroll
      for (int rt = 0; rt < NRT; ++rt)
#pragma unroll
        for (int c2 = 0; c2 < 2; ++c2) {
          int g = wv * 32 + c2 * 16 + (lane & 15);
#pragma unroll
          for (int r = 0; r < 4; ++r) {
            int u = rt * 16 + ((lane >> 4) << 2) + r;
            gates[u * GSTR + g] = acc[rt][c2][r];
          }
        }
    }
    __syncthreads();   // gates ready; A-tile reads done

    // ===== PW phase (wave-uniform skip; NO dead-step stores) =====
#pragma unroll
    for (int i = 0; i < NU; ++i) {
      int u = ug * NU + i;
      int n = n0 + u;
      int L = ulen[i];
      if (t < L) {
        if (MODE == 0) {
          float2 g0 = *(const float2*)&gates[u * GSTR + j2];
          float2 g1 = *(const float2*)&gates[u * GSTR + 128 + j2];
          float2 g2 = *(const float2*)&gates[u * GSTR + 256 + j2];
          float2 g3 = *(const float2*)&gates[u * GSTR + 384 + j2];
          float i0 = sigf(g0.x + b2[0].x), i1 = sigf(g0.y + b2[0].y);
          float f0 = sigf(g1.x + b2[1].x), f1 = sigf(g1.y + b2[1].y);
          float c0 = tanhfast(g2.x + b2[2].x), c1 = tanhfast(g2.y + b2[2].y);
          float o0 = sigf(g3.x + b2[3].x), o1 = sigf(g3.y + b2[3].y);
          float cA = f0 * cst0[i] + i0 * c0;
          float cB = f1 * cst1[i] + i1 * c1;
          cst0[i] = cA; cst1[i] = cB;
          unsigned hp = pack_bf(o0 * tanhfast(cA), o1 * tanhfast(cB));
          *(unsigned*)&ash[u * ASTR + 128 + j2] = hp;
          if (dir == 0) *(unsigned*)&outF[((size_t)t * NN + n) * 128 + j2] = hp;
          else          *(unsigned*)&outB[((size_t)(L - 1 - t) * NN + n) * 128 + j2] = hp;
        } else {
          float p0 = gates[u * GSTR + j2]       + b2[0].x;
          float p1 = gates[u * GSTR + 128 + j2] + b2[1].x;
          float p2 = gates[u * GSTR + 256 + j2] + b2[2].x;
          float p3 = gates[u * GSTR + 384 + j2] + b2[3].x;
          float ig = sigf(p0), fg = sigf(p1), gg = tanhfast(p2), og = sigf(p3);
          float c = fg * cst0[i] + ig * gg;
          cst0[i] = c;
          unsigned short hb = f2bf(og * tanhfast(c));
          ash[u * ASTR + 128 + j2] = hb;
          if (dir == 0) outF[((size_t)t * NN + n) * 128 + j2] = hb;
          else          outB[((size_t)(L - 1 - t) * NN + n) * 128 + j2] = hb;
        }
      }
      // t >= L: nothing — downstream GEMMs mask rows t >= len.
    }
    // x(t+1) into A-tile (prefetched during MFMA phase)
    if (t + 1 < TT) {
      if (MODE == 0) {
        short4x x4;
        x4[0] = (short)f2bf(xq.x); x4[1] = (short)f2bf(xq.y);
        x4[2] = (short)f2bf(xq.z); x4[3] = (short)f2bf(xq.w);
        *(short4x*)&ash[gu * ASTR + gk0] = x4;
      } else {
        ash[gu * ASTR + gk0] = xs;
      }
    }
    __syncthreads();   // h(t) + x(t+1) visible
  }
}

// ---------------------------------------------------------------------------
// MFMA GEMM: rows x 128, K=256, A = bf16 [INf|INb] from global, B resident.
// BOTH epilogues mask rows t >= lens[n] (A-frag zero -> OUT = bias; identical
// to what zero-stored dead rows produced, and those OUT rows carry zero
// softmax weight downstream).
// EPI 0: f32 store (final output).  EPI 1: bf16 OUT + fused LN/tanh/attn.
// ---------------------------------------------------------------------------
template <int EPI>
__global__ __launch_bounds__(256) void gemm_mfma(
    const unsigned short* __restrict__ INf, const unsigned short* __restrict__ INb,
    const int* __restrict__ lens,
    const unsigned short* __restrict__ Bfrag, const float* __restrict__ bias,
    void* __restrict__ OUTv, float* __restrict__ scores,
    const float* __restrict__ lng, const float* __restrict__ lnb,
    const float* __restrict__ attw, const float* __restrict__ attb,
    const int* __restrict__ units, int Nn)
{
  constexpr int OSTR = 132;
  __shared__ float outs[64 * OSTR];
  __shared__ float red1[256];
  __shared__ float red2[256];
  __shared__ float rowm[64], rowr[64];
  __shared__ float awsh[128], lgsh[128], lbsh[128];

  int tid = threadIdx.x, lane = tid & 63, wv = tid >> 6;
  int row0 = blockIdx.x * 64;
  int t = row0 / Nn, n0 = row0 % Nn;   // 64-row blocks never straddle t

  if (EPI == 1 && tid < 128) {
    awsh[tid] = attw[tid]; lgsh[tid] = lng[tid]; lbsh[tid] = lnb[tid];
  }

  short8 bfr[8][2];
#pragma unroll
  for (int ks = 0; ks < 8; ++ks)
#pragma unroll
    for (int c2 = 0; c2 < 2; ++c2) {
      int ct = wv * 2 + c2;
      bfr[ks][c2] = *(const short8*)&Bfrag[(((ct * 8 + ks) * 64) + lane) * 8];
    }

  int rb = lane & 15;
  int koq = (lane >> 4) << 3;
  bool val[4];
#pragma unroll
  for (int rt = 0; rt < 4; ++rt)
    val[rt] = (t < lens[n0 + rt * 16 + rb]);

  f32x4 acc[4][2];
#pragma unroll
  for (int rt = 0; rt < 4; ++rt)
#pragma unroll
    for (int c2 = 0; c2 < 2; ++c2) {
      f32x4 z = {0.f, 0.f, 0.f, 0.f};
      acc[rt][c2] = z;
    }

#pragma unroll
  for (int ks = 0; ks < 8; ++ks) {
    const unsigned short* P = (ks < 4) ? INf : INb;
    int koff = (ks & 3) * 32 + koq;
#pragma unroll
    for (int rt = 0; rt < 4; ++rt) {
      short8 a = {0, 0, 0, 0, 0, 0, 0, 0};
      if (val[rt])
        a = *(const short8*)&P[((size_t)(row0 + rt * 16 + rb)) * 128 + koff];
#pragma unroll
      for (int c2 = 0; c2 < 2; ++c2)
        acc[rt][c2] = __builtin_amdgcn_mfma_f32_16x16x32_bf16(
            a, bfr[ks][c2], acc[rt][c2], 0, 0, 0);
    }
  }

  float bc[2];
#pragma unroll
  for (int c2 = 0; c2 < 2; ++c2) bc[c2] = bias[wv * 32 + c2 * 16 + rb];
#pragma unroll
  for (int rt = 0; rt < 4; ++rt)
#pragma unroll
    for (int c2 = 0; c2 < 2; ++c2) {
      int col = wv * 32 + c2 * 16 + rb;
      int ub  = rt * 16 + ((lane >> 4) << 2);
#pragma unroll
      for (int r = 0; r < 4; ++r)
        outs[(ub + r) * OSTR + col] = acc[rt][c2][r] + bc[c2];
    }
  __syncthreads();

  int row = tid >> 2, seg = tid & 3;
  const float* rp = &outs[row * OSTR + seg * 32];
  size_t go = ((size_t)(row0 + row)) * 128 + seg * 32;

  if (EPI == 0) {
    float* OUT = (float*)OUTv;
#pragma unroll
    for (int x = 0; x < 8; ++x)
      *(f32x4*)&OUT[go + x * 4] = *(const f32x4*)&rp[x * 4];
  } else {
    unsigned short* OUT = (unsigned short*)OUTv;
    f32x4 v[8];
    float s = 0.f, s2 = 0.f;
#pragma unroll
    for (int x = 0; x < 8; ++x) {
      v[x] = *(const f32x4*)&rp[x * 4];
#pragma unroll
      for (int c = 0; c < 4; ++c) { s += v[x][c]; s2 += v[x][c] * v[x][c]; }
    }
    red1[tid] = s; red2[tid] = s2;
    __syncthreads();
    if (tid < 64) {
      float a = red1[tid * 4] + red1[tid * 4 + 1] + red1[tid * 4 + 2] + red1[tid * 4 + 3];
      float b = red2[tid * 4] + red2[tid * 4 + 1] + red2[tid * 4 + 2] + red2[tid * 4 + 3];
      float m = a * (1.f / 128.f);
      float var = b * (1.f / 128.f) - m * m;
      rowm[tid] = m;
      rowr[tid] = rsqrtf(var + 1e-5f);
    }
    __syncthreads();
    float m = rowm[row], rs = rowr[row];
    float sp = 0.f;
#pragma unroll
    for (int x = 0; x < 8; ++x) {
      short4x pv;
#pragma unroll
      for (int c = 0; c < 4; ++c) {
        int col = seg * 32 + x * 4 + c;
        float q = tanhfast((v[x][c] - m) * rs * lgsh[col] + lbsh[col]);
        sp += q * awsh[col];
        pv[c] = (short)f2bf(v[x][c]);
      }
      *(short4x*)&OUT[go + x * 4] = pv;   // bf16 intermediate (8B store)
    }
    red1[tid] = sp;
    __syncthreads();
    if (tid < 64) {
      float s3 = red1[tid * 4] + red1[tid * 4 + 1] + red1[tid * 4 + 2] + red1[tid * 4 + 3]
               + attb[0];
      int n = n0 + tid;
      if (units[t * NUNITS + n] == 0) s3 = -1e9f;
      scores[t * NUNITS + n] = s3;
    }
  }
}

// ---------------------------------------------------------------------------
// Softmax over T=16 + attention-weighted pooling -> tok_feat[n][e] (bf16:
// consumer rounds to bf16 at its LDS write anyway — bit-exact, halves the
// path-LSTM's scattered gather traffic).
// ---------------------------------------------------------------------------
__global__ __launch_bounds__(128) void softmax_feat_kernel(
    const float* __restrict__ scores, const unsigned short* __restrict__ out_lin,
    unsigned short* __restrict__ tok_feat)
{
  int n = blockIdx.x;
  int e = threadIdx.x;
  float s[T_TOKN];
  float m = -1e30f;
#pragma unroll
  for (int t = 0; t < T_TOKN; ++t) { s[t] = scores[t * NUNITS + n]; m = fmaxf(m, s[t]); }
  float sum = 0.f;
#pragma unroll
  for (int t = 0; t < T_TOKN; ++t) { s[t] = expf(s[t] - m); sum += s[t]; }
  float inv = 1.f / sum;
  float a = 0.f;
#pragma unroll
  for (int t = 0; t < T_TOKN; ++t)
    a += s[t] * inv * bf2f(out_lin[((size_t)t * NUNITS + n) * 128 + e]);
  tok_feat[n * 128 + e] = f2bf(a);
}

// ---------------------------------------------------------------------------
extern "C" void kernel_launch(void* const* d_in, const int* in_sizes, int n_in,
                              void* d_out, int out_size, void* d_ws, size_t ws_size,
                              hipStream_t stream)
{
  const int*   units = (const int*)d_in[0];
  const int*   paths = (const int*)d_in[1];
  const int*   upd   = (const int*)d_in[2];
  const int*   ppd   = (const int*)d_in[3];
  const float* emb   = (const float*)d_in[4];
  const float* tWif  = (const float*)d_in[5];
  const float* tWhf  = (const float*)d_in[6];
  const float* tbf   = (const float*)d_in[7];
  const float* tWib  = (const float*)d_in[8];
  const float* tWhb  = (const float*)d_in[9];
  const float* tbb   = (const float*)d_in[10];
  const float* linW  = (const float*)d_in[11];
  const float* linb  = (const float*)d_in[12];
  const float* lng   = (const float*)d_in[13];
  const float* lnb   = (const float*)d_in[14];
  const float* attw  = (const float*)d_in[15];
  const float* attb  = (const float*)d_in[16];
  const float* pWif  = (const float*)d_in[17];
  const float* pWhf  = (const float*)d_in[18];
  const float* pbf   = (const float*)d_in[19];
  const float* pWib  = (const float*)d_in[20];
  const float* pWhb  = (const float*)d_in[21];
  const float* pbb   = (const float*)d_in[22];
  const float* ulW   = (const float*)d_in[23];
  const float* ulb   = (const float*)d_in[24];

  float* ws = (float*)d_ws;
  int*   ip = (int*)(ws + OFF_INT);
  if (ws_size < WS_FLOATS * sizeof(float)) return;

  unsigned short* wfrag   = (unsigned short*)(ws + OFF_WFRAG);
  unsigned short* linfrag = (unsigned short*)(ws + OFF_LINFRAG);
  unsigned short* ulfrag  = linfrag + 32768;
  unsigned short* OUTF  = (unsigned short*)(ws + OFF_OUTF);
  unsigned short* OUTB  = (unsigned short*)(ws + OFF_OUTB);
  unsigned short* POUTF = (unsigned short*)(ws + OFF_POUTF);
  unsigned short* POUTB = (unsigned short*)(ws + OFF_POUTB);
  unsigned short* TOKF16 = (unsigned short*)(ws + OFF_TOKFEAT);

  prep_kernel<<<308, 256, 0, stream>>>(tWif, tWhf, tWib, tWhb,
                                       pWif, pWhf, pWib, pWhb,
                                       linW, ulW, units, paths, upd, ppd,
                                       ws, ip);

  lstm_kernel<0><<<dim3(128, 2), 1024, 0, stream>>>(
      wfrag, tbf, tbb, (const void*)emb, units, ip /*tok_len*/,
      nullptr, nullptr, nullptr, OUTF, OUTB);

  gemm_mfma<1><<<1024, 256, 0, stream>>>(
      OUTF, OUTB, ip /*tok_len*/, linfrag, linb,
      (void*)(ws + OFF_OUTLIN), ws + OFF_SCORES, lng, lnb, attw, attb, units, NUNITS);

  softmax_feat_kernel<<<4096, 128, 0, stream>>>(
      ws + OFF_SCORES, (const unsigned short*)(ws + OFF_OUTLIN), TOKF16);

  lstm_kernel<1><<<dim3(128, 2), 1024, 0, stream>>>(
      wfrag, pbf, pbb, (const void*)TOKF16, paths, ip + 5120 /*p_len*/,
      ip + 4096 /*fe*/, ip + 6144 /*off_p*/, ip + 7168 /*un_p*/,
      POUTF, POUTB);

  gemm_mfma<0><<<512, 256, 0, stream>>>(
      POUTF, POUTB, ip + 5120 /*p_len*/, ulfrag, ulb,
      (void*)d_out, nullptr, nullptr, nullptr, nullptr, nullptr, nullptr, NPATHS);
}

// Round 9
// 302.829 us; speedup vs baseline: 1.1570x; 1.0015x over previous
//
#include <hip/hip_runtime.h>
#include <cstdint>
#include <cstddef>

// Problem constants
#define T_TOKN 16
#define NUNITS 4096
#define LPATH  32
#define NPATHS 1024
#define BNUM   8

typedef __attribute__((ext_vector_type(8))) short short8;   // 8 bf16 in 4 VGPRs
typedef __attribute__((ext_vector_type(4))) short short4x;  // 4 bf16 in 2 VGPRs
typedef __attribute__((ext_vector_type(4))) float f32x4;    // MFMA accumulator

// ws float offsets
enum : size_t {
  OFF_WFRAG   = 0,                        // 524288 ushort: lstm W frags [tf|tb|pf|pb]
  OFF_LINFRAG = 262144,                   // 65536 ushort: lin/ul B-frags
  OFF_OUTF    = 294912,                   // token fwd h, bf16 16x4096x128
  OFF_OUTB    = OFF_OUTF + 4194304,       // token bwd h (time-realigned), bf16
  OFF_OUTLIN  = OFF_OUTB + 4194304,       // bf16 16x4096x128 (intermediate only)
  OFF_SCORES  = OFF_OUTLIN + 8388608,     // f32 16x4096
  OFF_TOKFEAT = OFF_SCORES + 65536,       // bf16 4096x128 (intermediate only)
  OFF_POUTF   = OFF_TOKFEAT + 524288,     // path fwd h, bf16 32x1024x128
  OFF_POUTB   = OFF_POUTF + 2097152,
  OFF_INT     = OFF_POUTB + 2097152,      // ints: tok_len 4096 | fe 1024 | p_len 1024 | off_p 1024 | un_p 1024
  WS_FLOATS   = OFF_INT + 8192
};

static __device__ __forceinline__ unsigned short f2bf(float f) {
  union { float f; unsigned u; } v; v.f = f;
  unsigned r = v.u + 0x7fffu + ((v.u >> 16) & 1u);
  return (unsigned short)(r >> 16);
}
static __device__ __forceinline__ float bf2f(unsigned short u) {
  union { unsigned u; float f; } v; v.u = ((unsigned)u) << 16;
  return v.f;
}
static __device__ __forceinline__ unsigned pack_bf(float a, float b) {
  return (unsigned)f2bf(a) | ((unsigned)f2bf(b) << 16);
}
static __device__ __forceinline__ float sigf(float x)      { return 1.f / (1.f + __expf(-x)); }
static __device__ __forceinline__ float tanhfast(float x)  { return 2.f / (1.f + __expf(-2.f * x)) - 1.f; }

// LDS-only barrier: waits LDS ops (lgkmcnt) but lets global stores/loads
// stay in flight across the barrier. Correct here because the barriers in
// the LSTM loop only protect LDS hazards (gates/h/x tiles); global h-stores
// are never re-read in-kernel, and global-load consumption is ordered by
// the compiler's dependency-driven waitcnt-before-use. Avoids the
// vmcnt(0) full drain hipcc emits for __syncthreads().
static __device__ __forceinline__ void barrier_lds() {
  asm volatile("s_waitcnt lgkmcnt(0)\n\ts_barrier" ::: "memory");
}

// ---------------------------------------------------------------------------
// prep (coalesced, r6-verified): thread = 8 consecutive k of one W row ->
// float4 x2 coalesced reads, aligned 16B short8 writes. Output bit layout
// identical to the r0/r5 consumers.
// ---------------------------------------------------------------------------
__global__ void prep_kernel(
    const float* __restrict__ tWif, const float* __restrict__ tWhf,
    const float* __restrict__ tWib, const float* __restrict__ tWhb,
    const float* __restrict__ pWif, const float* __restrict__ pWhf,
    const float* __restrict__ pWib, const float* __restrict__ pWhb,
    const float* __restrict__ linW, const float* __restrict__ ulW,
    const int* __restrict__ units, const int* __restrict__ paths,
    const int* __restrict__ upd, const int* __restrict__ ppd,
    float* __restrict__ ws, int* __restrict__ ip)
{
  int idx = blockIdx.x * 256 + threadIdx.x;
  if (idx < 65536) {
    unsigned short* wf = (unsigned short*)(ws + OFF_WFRAG);
    int k8 = idx & 31, g = (idx >> 5) & 511, mat = idx >> 14;
    const float* Wi; const float* Wh;
    switch (mat) {
      case 0: Wi = tWif; Wh = tWhf; break;
      case 1: Wi = tWib; Wh = tWhb; break;
      case 2: Wi = pWif; Wh = pWhf; break;
      default: Wi = pWib; Wh = pWhb; break;
    }
    int kb = k8 << 3;
    const float* sp = (kb < 128) ? (Wi + g * 128 + kb) : (Wh + g * 128 + (kb - 128));
    float4 a = *(const float4*)sp;
    float4 b = *(const float4*)(sp + 4);
    int wvp = g >> 6, ct = (g >> 4) & 3, cl = g & 15;
    int ks = k8 >> 2, quad = k8 & 3;
    size_t base = ((size_t)mat << 17) +
                  (size_t)(((((wvp * 8 + ks) * 4 + ct) * 64) + quad * 16 + cl) << 3);
    short8 o;
    o[0] = (short)f2bf(a.x); o[1] = (short)f2bf(a.y);
    o[2] = (short)f2bf(a.z); o[3] = (short)f2bf(a.w);
    o[4] = (short)f2bf(b.x); o[5] = (short)f2bf(b.y);
    o[6] = (short)f2bf(b.z); o[7] = (short)f2bf(b.w);
    *(short8*)&wf[base] = o;
  } else if (idx < 65536 + 8192) {
    unsigned short* lf = (unsigned short*)(ws + OFF_LINFRAG);
    int j = idx - 65536;
    int k8 = j & 31, e = (j >> 5) & 127, mat = j >> 12;
    const float* W = mat ? ulW : linW;
    int kb = k8 << 3;
    const float* sp = W + e * 256 + kb;
    float4 a = *(const float4*)sp;
    float4 b = *(const float4*)(sp + 4);
    int ct = e >> 4, cl = e & 15;
    int ks = k8 >> 2, quad = k8 & 3;
    size_t base = ((size_t)mat << 15) +
                  (size_t)((((ct * 8 + ks) * 64) + quad * 16 + cl) << 3);
    short8 o;
    o[0] = (short)f2bf(a.x); o[1] = (short)f2bf(a.y);
    o[2] = (short)f2bf(a.z); o[3] = (short)f2bf(a.w);
    o[4] = (short)f2bf(b.x); o[5] = (short)f2bf(b.y);
    o[6] = (short)f2bf(b.z); o[7] = (short)f2bf(b.w);
    *(short8*)&lf[base] = o;
  } else if (idx < 73728 + 4096) {
    int n = idx - 73728;
    int len = T_TOKN;
    for (int t = 0; t < T_TOKN; ++t)
      if (units[t * NUNITS + n] == 0) { len = t; break; }
    ip[n] = len;                                   // tok_len
  } else if (idx < 77824 + 1024) {
    int p = idx - 77824;
    int* fe_a  = ip + 4096;
    int* p_len = ip + 5120;
    int* off_p = ip + 6144;
    int* un_p  = ip + 7168;
    int cum = 0; int d = BNUM - 1;
    for (int dd = 0; dd < BNUM; ++dd) {
      int c2 = cum + ppd[dd];
      if (p < c2) { d = dd; break; }
      cum = c2;
    }
    int off = 0;
    for (int dd = 0; dd < d; ++dd) off += upd[dd];
    int un = upd[d];
    off_p[p] = off; un_p[p] = un;
    int f = LPATH;
    for (int t = 0; t < LPATH; ++t)
      if (paths[t * NPATHS + p] == -1) { f = t; break; }
    fe_a[p] = f;
    int pl = LPATH;
    for (int t = 0; t < LPATH; ++t) {
      int v = paths[t * NPATHS + p];
      if ((t >= f) || (v < 0) || (v > un)) { pl = t; break; }
    }
    p_len[p] = pl;
  }
}

// ---------------------------------------------------------------------------
// MFMA BiLSTM, 16-wave blocks, resident B (32 gate-cols/wave, 64 VGPR/lane).
// Round-9 = exact r8 structure (best: lstm0 = 79us) + LDS-only barriers in
// the steady-state loop: the in-loop barriers only protect LDS hazards, so
// s_waitcnt lgkmcnt(0)+s_barrier replaces __syncthreads(), letting global
// h-store acks and the x-gather prefetch ride across barriers instead of
// being force-drained by hipcc's vmcnt(0)-before-s_barrier.
// Keeps: idxL preload, wave-uniform dead-step transcendental skip, no
// dead-step stores (GEMMs mask t>=len rows), r0 phase order, bf16 OUTLIN,
// bf16 tok_feat source for MODE 1.
// MODE 0: token (emb gather f32, M=32, thread = 2 units x 2 cols).
// MODE 1: path (tok_feat bf16 gather w/ keep mask, M=8, scalar pointwise).
// ---------------------------------------------------------------------------
template <int MODE>
__global__ __launch_bounds__(1024, 4) void lstm_kernel(
    const unsigned short* __restrict__ wfragAll,
    const float* __restrict__ biasF, const float* __restrict__ biasB,
    const void* __restrict__ srcv,       // emb (f32) or tok_feat (bf16)
    const int* __restrict__ idxsrc,      // units or paths
    const int* __restrict__ lens,        // tok_len or p_len
    const int* __restrict__ fe_a, const int* __restrict__ off_p, const int* __restrict__ un_p,
    unsigned short* __restrict__ outF, unsigned short* __restrict__ outB)
{
  constexpr int NN   = MODE ? NPATHS : NUNITS;
  constexpr int TT   = MODE ? LPATH : T_TOKN;
  constexpr int M    = MODE ? 8 : 32;     // real sequences per block
  constexpr int MR   = MODE ? 16 : 32;    // MFMA tile rows
  constexpr int NRT  = MR / 16;
  constexpr int ASTR = 264;               // A-tile row stride (ushorts)
  constexpr int GSTR = 514;               // gates row stride (f32)

  __shared__ unsigned short ash[MR * ASTR];  // [u][0:128)=x  [u][128:256)=h
  __shared__ float gates[MR * GSTR];
  __shared__ int   idxL[M * TT];             // preloaded index columns

  const float* srcf = (const float*)srcv;                 // MODE 0
  const unsigned short* src16 = (const unsigned short*)srcv;  // MODE 1

  int tid  = threadIdx.x;
  int dir  = blockIdx.y;
  int n0   = blockIdx.x * M;
  int lane = tid & 63, wv = tid >> 6;       // wv in [0,16)

  // ---- resident B fragments: wave wv covers gates [wv*32, wv*32+32) ----
  const unsigned short* wbase =
      wfragAll + (size_t)((MODE ? 2 : 0) + dir) * 131072;
  int wv8 = wv >> 1;
  short8 bfr[8][2];
#pragma unroll
  for (int ks = 0; ks < 8; ++ks)
#pragma unroll
    for (int c2 = 0; c2 < 2; ++c2) {
      int ct = ((wv & 1) << 1) | c2;
      bfr[ks][c2] = *(const short8*)&wbase[((((wv8 * 8 + ks) * 4 + ct) * 64) + lane) * 8];
    }

  // ---- zero LDS (h region; MODE 1: whole tile incl dummy rows) ----
  if (MODE == 0) {
    for (int i = tid; i < MR * 128; i += 1024)
      ash[(i >> 7) * ASTR + 128 + (i & 127)] = 0;
  } else {
    for (int i = tid; i < MR * ASTR; i += 1024) ash[i] = 0;
  }
  // ---- preload idx columns: idxL[u*TT + t] = idxsrc[t*NN + n0+u] ----
  for (int i = tid; i < M * TT; i += 1024) {
    int u = i / TT, tt = i - u * TT;
    idxL[i] = idxsrc[tt * NN + (n0 + u)];
  }

  // ---- pointwise thread state ----
  const float* bcp = dir ? biasB : biasF;
  // MODE 0: thread = wave's unit pair x j pair.  MODE 1: 1 unit x 1 j.
  int j2 = MODE ? (tid & 127) : ((tid & 63) * 2);
  int ug = MODE ? (tid >> 7)  : (tid >> 6);
  float2 b2[4];
#pragma unroll
  for (int q = 0; q < 4; ++q) {
    if (MODE == 0) b2[q] = *(const float2*)&bcp[q * 128 + j2];
    else           b2[q] = make_float2(bcp[q * 128 + j2], 0.f);
  }
  constexpr int NU = MODE ? 1 : 2;          // units per pointwise thread
  float cst0[NU], cst1[NU];
  int   ulen[NU];
#pragma unroll
  for (int i = 0; i < NU; ++i) {
    cst0[i] = 0.f; cst1[i] = 0.f;
    ulen[i] = lens[n0 + ug * NU + i];
  }

  // ---- gather thread state ----
  int gu, gk0;
  if (MODE == 0) { gu = tid >> 5; gk0 = (tid & 31) * 4; }   // 32 rows x 32 thr
  else           { gu = tid >> 7; gk0 = tid & 127; }        // 8 rows x 128 thr
  int gn = n0 + gu;
  int glen = lens[gn];
  int gfe = 0, goff = 0, gun = 0;
  if (MODE) { gfe = fe_a[gn]; goff = off_p[gn]; gun = un_p[gn]; }

  float4 xq; unsigned short xs;
  __syncthreads();   // zeros + idxL visible (full barrier: preamble only)

  // ---- preamble: load + write x(0) ----
  {
    int tau = dir ? min(max(glen - 1, 0), TT - 1) : 0;
    int v = idxL[gu * TT + tau];
    if (MODE == 0) {
      xq = *(const float4*)&srcf[(size_t)v * 128 + gk0];
    } else {
      bool keep = (tau < gfe) && (v >= 0) && (v < gun);
      xs = keep ? src16[(size_t)min(v + goff, NUNITS - 1) * 128 + gk0] : (unsigned short)0;
    }
  }
  if (MODE == 0) {
    short4x x4;
    x4[0] = (short)f2bf(xq.x); x4[1] = (short)f2bf(xq.y);
    x4[2] = (short)f2bf(xq.z); x4[3] = (short)f2bf(xq.w);
    *(short4x*)&ash[gu * ASTR + gk0] = x4;
  } else {
    ash[gu * ASTR + gk0] = xs;
  }
  __syncthreads();   // x(0) visible

#pragma unroll 1
  for (int t = 0; t < TT; ++t) {
    // ===== MFMA phase (r0 ordering) =====
    {
      int tn = (t + 1 < TT) ? t + 1 : t;
      int taun = dir ? min(max(glen - 1 - tn, 0), TT - 1) : tn;
      int vn = idxL[gu * TT + taun];     // LDS read; no global idx chain
      f32x4 acc[NRT][2];
#pragma unroll
      for (int rt = 0; rt < NRT; ++rt)
#pragma unroll
        for (int c2 = 0; c2 < 2; ++c2) {
          f32x4 z = {0.f, 0.f, 0.f, 0.f};
          acc[rt][c2] = z;
        }
#pragma unroll
      for (int ks = 0; ks < 8; ++ks) {
        short8 afr[NRT];
#pragma unroll
        for (int rt = 0; rt < NRT; ++rt)
          afr[rt] = *(const short8*)&ash[(rt * 16 + (lane & 15)) * ASTR + ks * 32 + ((lane >> 4) << 3)];
#pragma unroll
        for (int rt = 0; rt < NRT; ++rt)
#pragma unroll
          for (int c2 = 0; c2 < 2; ++c2)
            acc[rt][c2] = __builtin_amdgcn_mfma_f32_16x16x32_bf16(
                afr[rt], bfr[ks][c2], acc[rt][c2], 0, 0, 0);
      }
      // dependent x(t+1) load — with LDS-only barriers its latency now
      // spans into the NEXT phase (drains at use, not at the barrier)
      if (MODE == 0) {
        xq = *(const float4*)&srcf[(size_t)vn * 128 + gk0];
      } else {
        bool keep = (taun < gfe) && (vn >= 0) && (vn < gun);
        xs = keep ? src16[(size_t)min(vn + goff, NUNITS - 1) * 128 + gk0] : (unsigned short)0;
      }
      // preacts -> LDS gates (C-layout: col=lane&15, row=quad*4+reg)
#pragma unroll
      for (int rt = 0; rt < NRT; ++rt)
#pragma unroll
        for (int c2 = 0; c2 < 2; ++c2) {
          int g = wv * 32 + c2 * 16 + (lane & 15);
#pragma unroll
          for (int r = 0; r < 4; ++r) {
            int u = rt * 16 + ((lane >> 4) << 2) + r;
            gates[u * GSTR + g] = acc[rt][c2][r];
          }
        }
    }
    barrier_lds();   // gates ready; A-tile reads done (LDS-only drain)

    // ===== PW phase (wave-uniform skip; NO dead-step stores) =====
#pragma unroll
    for (int i = 0; i < NU; ++i) {
      int u = ug * NU + i;
      int n = n0 + u;
      int L = ulen[i];
      if (t < L) {
        if (MODE == 0) {
          float2 g0 = *(const float2*)&gates[u * GSTR + j2];
          float2 g1 = *(const float2*)&gates[u * GSTR + 128 + j2];
          float2 g2 = *(const float2*)&gates[u * GSTR + 256 + j2];
          float2 g3 = *(const float2*)&gates[u * GSTR + 384 + j2];
          float i0 = sigf(g0.x + b2[0].x), i1 = sigf(g0.y + b2[0].y);
          float f0 = sigf(g1.x + b2[1].x), f1 = sigf(g1.y + b2[1].y);
          float c0 = tanhfast(g2.x + b2[2].x), c1 = tanhfast(g2.y + b2[2].y);
          float o0 = sigf(g3.x + b2[3].x), o1 = sigf(g3.y + b2[3].y);
          float cA = f0 * cst0[i] + i0 * c0;
          float cB = f1 * cst1[i] + i1 * c1;
          cst0[i] = cA; cst1[i] = cB;
          unsigned hp = pack_bf(o0 * tanhfast(cA), o1 * tanhfast(cB));
          *(unsigned*)&ash[u * ASTR + 128 + j2] = hp;
          if (dir == 0) *(unsigned*)&outF[((size_t)t * NN + n) * 128 + j2] = hp;
          else          *(unsigned*)&outB[((size_t)(L - 1 - t) * NN + n) * 128 + j2] = hp;
        } else {
          float p0 = gates[u * GSTR + j2]       + b2[0].x;
          float p1 = gates[u * GSTR + 128 + j2] + b2[1].x;
          float p2 = gates[u * GSTR + 256 + j2] + b2[2].x;
          float p3 = gates[u * GSTR + 384 + j2] + b2[3].x;
          float ig = sigf(p0), fg = sigf(p1), gg = tanhfast(p2), og = sigf(p3);
          float c = fg * cst0[i] + ig * gg;
          cst0[i] = c;
          unsigned short hb = f2bf(og * tanhfast(c));
          ash[u * ASTR + 128 + j2] = hb;
          if (dir == 0) outF[((size_t)t * NN + n) * 128 + j2] = hb;
          else          outB[((size_t)(L - 1 - t) * NN + n) * 128 + j2] = hb;
        }
      }
      // t >= L: nothing — downstream GEMMs mask rows t >= len.
    }
    // x(t+1) into A-tile (prefetched during MFMA phase)
    if (t + 1 < TT) {
      if (MODE == 0) {
        short4x x4;
        x4[0] = (short)f2bf(xq.x); x4[1] = (short)f2bf(xq.y);
        x4[2] = (short)f2bf(xq.z); x4[3] = (short)f2bf(xq.w);
        *(short4x*)&ash[gu * ASTR + gk0] = x4;
      } else {
        ash[gu * ASTR + gk0] = xs;
      }
    }
    barrier_lds();   // h(t) + x(t+1) visible (LDS-only drain)
  }
}

// ---------------------------------------------------------------------------
// MFMA GEMM: rows x 128, K=256, A = bf16 [INf|INb] from global, B resident.
// BOTH epilogues mask rows t >= lens[n] (A-frag zero -> OUT = bias; identical
// to what zero-stored dead rows produced, and those OUT rows carry zero
// softmax weight downstream).
// EPI 0: f32 store (final output).  EPI 1: bf16 OUT + fused LN/tanh/attn.
// ---------------------------------------------------------------------------
template <int EPI>
__global__ __launch_bounds__(256) void gemm_mfma(
    const unsigned short* __restrict__ INf, const unsigned short* __restrict__ INb,
    const int* __restrict__ lens,
    const unsigned short* __restrict__ Bfrag, const float* __restrict__ bias,
    void* __restrict__ OUTv, float* __restrict__ scores,
    const float* __restrict__ lng, const float* __restrict__ lnb,
    const float* __restrict__ attw, const float* __restrict__ attb,
    const int* __restrict__ units, int Nn)
{
  constexpr int OSTR = 132;
  __shared__ float outs[64 * OSTR];
  __shared__ float red1[256];
  __shared__ float red2[256];
  __shared__ float rowm[64], rowr[64];
  __shared__ float awsh[128], lgsh[128], lbsh[128];

  int tid = threadIdx.x, lane = tid & 63, wv = tid >> 6;
  int row0 = blockIdx.x * 64;
  int t = row0 / Nn, n0 = row0 % Nn;   // 64-row blocks never straddle t

  if (EPI == 1 && tid < 128) {
    awsh[tid] = attw[tid]; lgsh[tid] = lng[tid]; lbsh[tid] = lnb[tid];
  }

  short8 bfr[8][2];
#pragma unroll
  for (int ks = 0; ks < 8; ++ks)
#pragma unroll
    for (int c2 = 0; c2 < 2; ++c2) {
      int ct = wv * 2 + c2;
      bfr[ks][c2] = *(const short8*)&Bfrag[(((ct * 8 + ks) * 64) + lane) * 8];
    }

  int rb = lane & 15;
  int koq = (lane >> 4) << 3;
  bool val[4];
#pragma unroll
  for (int rt = 0; rt < 4; ++rt)
    val[rt] = (t < lens[n0 + rt * 16 + rb]);

  f32x4 acc[4][2];
#pragma unroll
  for (int rt = 0; rt < 4; ++rt)
#pragma unroll
    for (int c2 = 0; c2 < 2; ++c2) {
      f32x4 z = {0.f, 0.f, 0.f, 0.f};
      acc[rt][c2] = z;
    }

#pragma unroll
  for (int ks = 0; ks < 8; ++ks) {
    const unsigned short* P = (ks < 4) ? INf : INb;
    int koff = (ks & 3) * 32 + koq;
#pragma unroll
    for (int rt = 0; rt < 4; ++rt) {
      short8 a = {0, 0, 0, 0, 0, 0, 0, 0};
      if (val[rt])
        a = *(const short8*)&P[((size_t)(row0 + rt * 16 + rb)) * 128 + koff];
#pragma unroll
      for (int c2 = 0; c2 < 2; ++c2)
        acc[rt][c2] = __builtin_amdgcn_mfma_f32_16x16x32_bf16(
            a, bfr[ks][c2], acc[rt][c2], 0, 0, 0);
    }
  }

  float bc[2];
#pragma unroll
  for (int c2 = 0; c2 < 2; ++c2) bc[c2] = bias[wv * 32 + c2 * 16 + rb];
#pragma unroll
  for (int rt = 0; rt < 4; ++rt)
#pragma unroll
    for (int c2 = 0; c2 < 2; ++c2) {
      int col = wv * 32 + c2 * 16 + rb;
      int ub  = rt * 16 + ((lane >> 4) << 2);
#pragma unroll
      for (int r = 0; r < 4; ++r)
        outs[(ub + r) * OSTR + col] = acc[rt][c2][r] + bc[c2];
    }
  __syncthreads();

  int row = tid >> 2, seg = tid & 3;
  const float* rp = &outs[row * OSTR + seg * 32];
  size_t go = ((size_t)(row0 + row)) * 128 + seg * 32;

  if (EPI == 0) {
    float* OUT = (float*)OUTv;
#pragma unroll
    for (int x = 0; x < 8; ++x)
      *(f32x4*)&OUT[go + x * 4] = *(const f32x4*)&rp[x * 4];
  } else {
    unsigned short* OUT = (unsigned short*)OUTv;
    f32x4 v[8];
    float s = 0.f, s2 = 0.f;
#pragma unroll
    for (int x = 0; x < 8; ++x) {
      v[x] = *(const f32x4*)&rp[x * 4];
#pragma unroll
      for (int c = 0; c < 4; ++c) { s += v[x][c]; s2 += v[x][c] * v[x][c]; }
    }
    red1[tid] = s; red2[tid] = s2;
    __syncthreads();
    if (tid < 64) {
      float a = red1[tid * 4] + red1[tid * 4 + 1] + red1[tid * 4 + 2] + red1[tid * 4 + 3];
      float b = red2[tid * 4] + red2[tid * 4 + 1] + red2[tid * 4 + 2] + red2[tid * 4 + 3];
      float m = a * (1.f / 128.f);
      float var = b * (1.f / 128.f) - m * m;
      rowm[tid] = m;
      rowr[tid] = rsqrtf(var + 1e-5f);
    }
    __syncthreads();
    float m = rowm[row], rs = rowr[row];
    float sp = 0.f;
#pragma unroll
    for (int x = 0; x < 8; ++x) {
      short4x pv;
#pragma unroll
      for (int c = 0; c < 4; ++c) {
        int col = seg * 32 + x * 4 + c;
        float q = tanhfast((v[x][c] - m) * rs * lgsh[col] + lbsh[col]);
        sp += q * awsh[col];
        pv[c] = (short)f2bf(v[x][c]);
      }
      *(short4x*)&OUT[go + x * 4] = pv;   // bf16 intermediate (8B store)
    }
    red1[tid] = sp;
    __syncthreads();
    if (tid < 64) {
      float s3 = red1[tid * 4] + red1[tid * 4 + 1] + red1[tid * 4 + 2] + red1[tid * 4 + 3]
               + attb[0];
      int n = n0 + tid;
      if (units[t * NUNITS + n] == 0) s3 = -1e9f;
      scores[t * NUNITS + n] = s3;
    }
  }
}

// ---------------------------------------------------------------------------
// Softmax over T=16 + attention-weighted pooling -> tok_feat[n][e] (bf16:
// consumer rounds to bf16 at its LDS write anyway — bit-exact, halves the
// path-LSTM's scattered gather traffic).
// ---------------------------------------------------------------------------
__global__ __launch_bounds__(128) void softmax_feat_kernel(
    const float* __restrict__ scores, const unsigned short* __restrict__ out_lin,
    unsigned short* __restrict__ tok_feat)
{
  int n = blockIdx.x;
  int e = threadIdx.x;
  float s[T_TOKN];
  float m = -1e30f;
#pragma unroll
  for (int t = 0; t < T_TOKN; ++t) { s[t] = scores[t * NUNITS + n]; m = fmaxf(m, s[t]); }
  float sum = 0.f;
#pragma unroll
  for (int t = 0; t < T_TOKN; ++t) { s[t] = expf(s[t] - m); sum += s[t]; }
  float inv = 1.f / sum;
  float a = 0.f;
#pragma unroll
  for (int t = 0; t < T_TOKN; ++t)
    a += s[t] * inv * bf2f(out_lin[((size_t)t * NUNITS + n) * 128 + e]);
  tok_feat[n * 128 + e] = f2bf(a);
}

// ---------------------------------------------------------------------------
extern "C" void kernel_launch(void* const* d_in, const int* in_sizes, int n_in,
                              void* d_out, int out_size, void* d_ws, size_t ws_size,
                              hipStream_t stream)
{
  const int*   units = (const int*)d_in[0];
  const int*   paths = (const int*)d_in[1];
  const int*   upd   = (const int*)d_in[2];
  const int*   ppd   = (const int*)d_in[3];
  const float* emb   = (const float*)d_in[4];
  const float* tWif  = (const float*)d_in[5];
  const float* tWhf  = (const float*)d_in[6];
  const float* tbf   = (const float*)d_in[7];
  const float* tWib  = (const float*)d_in[8];
  const float* tWhb  = (const float*)d_in[9];
  const float* tbb   = (const float*)d_in[10];
  const float* linW  = (const float*)d_in[11];
  const float* linb  = (const float*)d_in[12];
  const float* lng   = (const float*)d_in[13];
  const float* lnb   = (const float*)d_in[14];
  const float* attw  = (const float*)d_in[15];
  const float* attb  = (const float*)d_in[16];
  const float* pWif  = (const float*)d_in[17];
  const float* pWhf  = (const float*)d_in[18];
  const float* pbf   = (const float*)d_in[19];
  const float* pWib  = (const float*)d_in[20];
  const float* pWhb  = (const float*)d_in[21];
  const float* pbb   = (const float*)d_in[22];
  const float* ulW   = (const float*)d_in[23];
  const float* ulb   = (const float*)d_in[24];

  float* ws = (float*)d_ws;
  int*   ip = (int*)(ws + OFF_INT);
  if (ws_size < WS_FLOATS * sizeof(float)) return;

  unsigned short* wfrag   = (unsigned short*)(ws + OFF_WFRAG);
  unsigned short* linfrag = (unsigned short*)(ws + OFF_LINFRAG);
  unsigned short* ulfrag  = linfrag + 32768;
  unsigned short* OUTF  = (unsigned short*)(ws + OFF_OUTF);
  unsigned short* OUTB  = (unsigned short*)(ws + OFF_OUTB);
  unsigned short* POUTF = (unsigned short*)(ws + OFF_POUTF);
  unsigned short* POUTB = (unsigned short*)(ws + OFF_POUTB);
  unsigned short* TOKF16 = (unsigned short*)(ws + OFF_TOKFEAT);

  prep_kernel<<<308, 256, 0, stream>>>(tWif, tWhf, tWib, tWhb,
                                       pWif, pWhf, pWib, pWhb,
                                       linW, ulW, units, paths, upd, ppd,
                                       ws, ip);

  lstm_kernel<0><<<dim3(128, 2), 1024, 0, stream>>>(
      wfrag, tbf, tbb, (const void*)emb, units, ip /*tok_len*/,
      nullptr, nullptr, nullptr, OUTF, OUTB);

  gemm_mfma<1><<<1024, 256, 0, stream>>>(
      OUTF, OUTB, ip /*tok_len*/, linfrag, linb,
      (void*)(ws + OFF_OUTLIN), ws + OFF_SCORES, lng, lnb, attw, attb, units, NUNITS);

  softmax_feat_kernel<<<4096, 128, 0, stream>>>(
      ws + OFF_SCORES, (const unsigned short*)(ws + OFF_OUTLIN), TOKF16);

  lstm_kernel<1><<<dim3(128, 2), 1024, 0, stream>>>(
      wfrag, pbf, pbb, (const void*)TOKF16, paths, ip + 5120 /*p_len*/,
      ip + 4096 /*fe*/, ip + 6144 /*off_p*/, ip + 7168 /*un_p*/,
      POUTF, POUTB);

  gemm_mfma<0><<<512, 256, 0, stream>>>(
      POUTF, POUTB, ip + 5120 /*p_len*/, ulfrag, ulb,
      (void*)d_out, nullptr, nullptr, nullptr, nullptr, nullptr, nullptr, NPATHS);
}

// Round 12
// 298.195 us; speedup vs baseline: 1.1750x; 1.0155x over previous
//
#include <hip/hip_runtime.h>
#include <cstdint>
#include <cstddef>

// Problem constants
#define T_TOKN 16
#define NUNITS 4096
#define LPATH  32
#define NPATHS 1024
#define BNUM   8

typedef __attribute__((ext_vector_type(8))) short short8;   // 8 bf16 in 4 VGPRs
typedef __attribute__((ext_vector_type(4))) short short4x;  // 4 bf16 in 2 VGPRs
typedef __attribute__((ext_vector_type(4))) float f32x4;    // MFMA accumulator

// ws float offsets
enum : size_t {
  OFF_WFRAG   = 0,                        // 524288 ushort: lstm W frags [tf|tb|pf|pb]
  OFF_LINFRAG = 262144,                   // 65536 ushort: lin/ul B-frags
  OFF_OUTF    = 294912,                   // token fwd h, bf16 16x4096x128
  OFF_OUTB    = OFF_OUTF + 4194304,       // token bwd h (time-realigned), bf16
  OFF_OUTLIN  = OFF_OUTB + 4194304,       // bf16 16x4096x128 (intermediate only)
  OFF_SCORES  = OFF_OUTLIN + 8388608,     // f32 16x4096
  OFF_TOKFEAT = OFF_SCORES + 65536,       // bf16 4096x128 (intermediate only)
  OFF_POUTF   = OFF_TOKFEAT + 524288,     // path fwd h, bf16 32x1024x128
  OFF_POUTB   = OFF_POUTF + 2097152,
  OFF_INT     = OFF_POUTB + 2097152,      // ints: tok_len 4096 | fe 1024 | p_len 1024 | off_p 1024 | un_p 1024
  WS_FLOATS   = OFF_INT + 8192
};

static __device__ __forceinline__ unsigned short f2bf(float f) {
  union { float f; unsigned u; } v; v.f = f;
  unsigned r = v.u + 0x7fffu + ((v.u >> 16) & 1u);
  return (unsigned short)(r >> 16);
}
static __device__ __forceinline__ float bf2f(unsigned short u) {
  union { unsigned u; float f; } v; v.u = ((unsigned)u) << 16;
  return v.f;
}
static __device__ __forceinline__ unsigned pack_bf(float a, float b) {
  return (unsigned)f2bf(a) | ((unsigned)f2bf(b) << 16);
}
static __device__ __forceinline__ float sigf(float x)      { return 1.f / (1.f + __expf(-x)); }
static __device__ __forceinline__ float tanhfast(float x)  { return 2.f / (1.f + __expf(-2.f * x)) - 1.f; }

// LDS-only barrier (r9-verified): waits LDS ops but not global loads/stores.
// All in-loop hazards are LDS-only; global h-stores are never re-read
// in-kernel and global-load use is compiler-waitcnt-ordered.
static __device__ __forceinline__ void barrier_lds() {
  asm volatile("s_waitcnt lgkmcnt(0)\n\ts_barrier" ::: "memory");
}

// ---------------------------------------------------------------------------
// prep (coalesced, r6-verified): thread = 8 consecutive k of one W row ->
// float4 x2 coalesced reads, aligned 16B short8 writes. Output bit layout
// identical to the r0/r5 consumers.
// ---------------------------------------------------------------------------
__global__ void prep_kernel(
    const float* __restrict__ tWif, const float* __restrict__ tWhf,
    const float* __restrict__ tWib, const float* __restrict__ tWhb,
    const float* __restrict__ pWif, const float* __restrict__ pWhf,
    const float* __restrict__ pWib, const float* __restrict__ pWhb,
    const float* __restrict__ linW, const float* __restrict__ ulW,
    const int* __restrict__ units, const int* __restrict__ paths,
    const int* __restrict__ upd, const int* __restrict__ ppd,
    float* __restrict__ ws, int* __restrict__ ip)
{
  int idx = blockIdx.x * 256 + threadIdx.x;
  if (idx < 65536) {
    unsigned short* wf = (unsigned short*)(ws + OFF_WFRAG);
    int k8 = idx & 31, g = (idx >> 5) & 511, mat = idx >> 14;
    const float* Wi; const float* Wh;
    switch (mat) {
      case 0: Wi = tWif; Wh = tWhf; break;
      case 1: Wi = tWib; Wh = tWhb; break;
      case 2: Wi = pWif; Wh = pWhf; break;
      default: Wi = pWib; Wh = pWhb; break;
    }
    int kb = k8 << 3;
    const float* sp = (kb < 128) ? (Wi + g * 128 + kb) : (Wh + g * 128 + (kb - 128));
    float4 a = *(const float4*)sp;
    float4 b = *(const float4*)(sp + 4);
    int wvp = g >> 6, ct = (g >> 4) & 3, cl = g & 15;
    int ks = k8 >> 2, quad = k8 & 3;
    size_t base = ((size_t)mat << 17) +
                  (size_t)(((((wvp * 8 + ks) * 4 + ct) * 64) + quad * 16 + cl) << 3);
    short8 o;
    o[0] = (short)f2bf(a.x); o[1] = (short)f2bf(a.y);
    o[2] = (short)f2bf(a.z); o[3] = (short)f2bf(a.w);
    o[4] = (short)f2bf(b.x); o[5] = (short)f2bf(b.y);
    o[6] = (short)f2bf(b.z); o[7] = (short)f2bf(b.w);
    *(short8*)&wf[base] = o;
  } else if (idx < 65536 + 8192) {
    unsigned short* lf = (unsigned short*)(ws + OFF_LINFRAG);
    int j = idx - 65536;
    int k8 = j & 31, e = (j >> 5) & 127, mat = j >> 12;
    const float* W = mat ? ulW : linW;
    int kb = k8 << 3;
    const float* sp = W + e * 256 + kb;
    float4 a = *(const float4*)sp;
    float4 b = *(const float4*)(sp + 4);
    int ct = e >> 4, cl = e & 15;
    int ks = k8 >> 2, quad = k8 & 3;
    size_t base = ((size_t)mat << 15) +
                  (size_t)((((ct * 8 + ks) * 64) + quad * 16 + cl) << 3);
    short8 o;
    o[0] = (short)f2bf(a.x); o[1] = (short)f2bf(a.y);
    o[2] = (short)f2bf(a.z); o[3] = (short)f2bf(a.w);
    o[4] = (short)f2bf(b.x); o[5] = (short)f2bf(b.y);
    o[6] = (short)f2bf(b.z); o[7] = (short)f2bf(b.w);
    *(short8*)&lf[base] = o;
  } else if (idx < 73728 + 4096) {
    int n = idx - 73728;
    int len = T_TOKN;
    for (int t = 0; t < T_TOKN; ++t)
      if (units[t * NUNITS + n] == 0) { len = t; break; }
    ip[n] = len;                                   // tok_len
  } else if (idx < 77824 + 1024) {
    int p = idx - 77824;
    int* fe_a  = ip + 4096;
    int* p_len = ip + 5120;
    int* off_p = ip + 6144;
    int* un_p  = ip + 7168;
    int cum = 0; int d = BNUM - 1;
    for (int dd = 0; dd < BNUM; ++dd) {
      int c2 = cum + ppd[dd];
      if (p < c2) { d = dd; break; }
      cum = c2;
    }
    int off = 0;
    for (int dd = 0; dd < d; ++dd) off += upd[dd];
    int un = upd[d];
    off_p[p] = off; un_p[p] = un;
    int f = LPATH;
    for (int t = 0; t < LPATH; ++t)
      if (paths[t * NPATHS + p] == -1) { f = t; break; }
    fe_a[p] = f;
    int pl = LPATH;
    for (int t = 0; t < LPATH; ++t) {
      int v = paths[t * NPATHS + p];
      if ((t >= f) || (v < 0) || (v > un)) { pl = t; break; }
    }
    p_len[p] = pl;
  }
}

// ---------------------------------------------------------------------------
// MFMA BiLSTM, 16-wave blocks, resident B (32 gate-cols/wave, 64 VGPR/lane).
// = r9 EXACTLY (known-good, 302.8us total). After two container failures on
// the r10 gate-ownership source, this round re-establishes the known-good
// core to disambiguate infra-vs-kernel; only the softmax kernel below is
// changed (launch-config + vectorization, bit-identical math).
// Keeps: idxL preload, wave-uniform dead-step transcendental skip, no
// dead-step stores (GEMMs mask t>=len rows), r0 phase order, bf16 OUTLIN,
// bf16 tok_feat source for MODE 1, LDS-only in-loop barriers.
// MODE 0: token (emb gather f32, M=32, thread = 2 units x 2 cols).
// MODE 1: path (tok_feat bf16 gather w/ keep mask, M=8, scalar pointwise).
// ---------------------------------------------------------------------------
template <int MODE>
__global__ __launch_bounds__(1024, 4) void lstm_kernel(
    const unsigned short* __restrict__ wfragAll,
    const float* __restrict__ biasF, const float* __restrict__ biasB,
    const void* __restrict__ srcv,       // emb (f32) or tok_feat (bf16)
    const int* __restrict__ idxsrc,      // units or paths
    const int* __restrict__ lens,        // tok_len or p_len
    const int* __restrict__ fe_a, const int* __restrict__ off_p, const int* __restrict__ un_p,
    unsigned short* __restrict__ outF, unsigned short* __restrict__ outB)
{
  constexpr int NN   = MODE ? NPATHS : NUNITS;
  constexpr int TT   = MODE ? LPATH : T_TOKN;
  constexpr int M    = MODE ? 8 : 32;     // real sequences per block
  constexpr int MR   = MODE ? 16 : 32;    // MFMA tile rows
  constexpr int NRT  = MR / 16;
  constexpr int ASTR = 264;               // A-tile row stride (ushorts)
  constexpr int GSTR = 514;               // gates row stride (f32)

  __shared__ unsigned short ash[MR * ASTR];  // [u][0:128)=x  [u][128:256)=h
  __shared__ float gates[MR * GSTR];
  __shared__ int   idxL[M * TT];             // preloaded index columns

  const float* srcf = (const float*)srcv;                 // MODE 0
  const unsigned short* src16 = (const unsigned short*)srcv;  // MODE 1

  int tid  = threadIdx.x;
  int dir  = blockIdx.y;
  int n0   = blockIdx.x * M;
  int lane = tid & 63, wv = tid >> 6;       // wv in [0,16)

  // ---- resident B fragments: wave wv covers gates [wv*32, wv*32+32) ----
  const unsigned short* wbase =
      wfragAll + (size_t)((MODE ? 2 : 0) + dir) * 131072;
  int wv8 = wv >> 1;
  short8 bfr[8][2];
#pragma unroll
  for (int ks = 0; ks < 8; ++ks)
#pragma unroll
    for (int c2 = 0; c2 < 2; ++c2) {
      int ct = ((wv & 1) << 1) | c2;
      bfr[ks][c2] = *(const short8*)&wbase[((((wv8 * 8 + ks) * 4 + ct) * 64) + lane) * 8];
    }

  // ---- zero LDS (h region; MODE 1: whole tile incl dummy rows) ----
  if (MODE == 0) {
    for (int i = tid; i < MR * 128; i += 1024)
      ash[(i >> 7) * ASTR + 128 + (i & 127)] = 0;
  } else {
    for (int i = tid; i < MR * ASTR; i += 1024) ash[i] = 0;
  }
  // ---- preload idx columns: idxL[u*TT + t] = idxsrc[t*NN + n0+u] ----
  for (int i = tid; i < M * TT; i += 1024) {
    int u = i / TT, tt = i - u * TT;
    idxL[i] = idxsrc[tt * NN + (n0 + u)];
  }

  // ---- pointwise thread state ----
  const float* bcp = dir ? biasB : biasF;
  // MODE 0: thread = wave's unit pair x j pair.  MODE 1: 1 unit x 1 j.
  int j2 = MODE ? (tid & 127) : ((tid & 63) * 2);
  int ug = MODE ? (tid >> 7)  : (tid >> 6);
  float2 b2[4];
#pragma unroll
  for (int q = 0; q < 4; ++q) {
    if (MODE == 0) b2[q] = *(const float2*)&bcp[q * 128 + j2];
    else           b2[q] = make_float2(bcp[q * 128 + j2], 0.f);
  }
  constexpr int NU = MODE ? 1 : 2;          // units per pointwise thread
  float cst0[NU], cst1[NU];
  int   ulen[NU];
#pragma unroll
  for (int i = 0; i < NU; ++i) {
    cst0[i] = 0.f; cst1[i] = 0.f;
    ulen[i] = lens[n0 + ug * NU + i];
  }

  // ---- gather thread state ----
  int gu, gk0;
  if (MODE == 0) { gu = tid >> 5; gk0 = (tid & 31) * 4; }   // 32 rows x 32 thr
  else           { gu = tid >> 7; gk0 = tid & 127; }        // 8 rows x 128 thr
  int gn = n0 + gu;
  int glen = lens[gn];
  int gfe = 0, goff = 0, gun = 0;
  if (MODE) { gfe = fe_a[gn]; goff = off_p[gn]; gun = un_p[gn]; }

  float4 xq; unsigned short xs;
  __syncthreads();   // zeros + idxL visible (full barrier: preamble only)

  // ---- preamble: load + write x(0) ----
  {
    int tau = dir ? min(max(glen - 1, 0), TT - 1) : 0;
    int v = idxL[gu * TT + tau];
    if (MODE == 0) {
      xq = *(const float4*)&srcf[(size_t)v * 128 + gk0];
    } else {
      bool keep = (tau < gfe) && (v >= 0) && (v < gun);
      xs = keep ? src16[(size_t)min(v + goff, NUNITS - 1) * 128 + gk0] : (unsigned short)0;
    }
  }
  if (MODE == 0) {
    short4x x4;
    x4[0] = (short)f2bf(xq.x); x4[1] = (short)f2bf(xq.y);
    x4[2] = (short)f2bf(xq.z); x4[3] = (short)f2bf(xq.w);
    *(short4x*)&ash[gu * ASTR + gk0] = x4;
  } else {
    ash[gu * ASTR + gk0] = xs;
  }
  __syncthreads();   // x(0) visible

#pragma unroll 1
  for (int t = 0; t < TT; ++t) {
    // ===== MFMA phase (r0 ordering) =====
    {
      int tn = (t + 1 < TT) ? t + 1 : t;
      int taun = dir ? min(max(glen - 1 - tn, 0), TT - 1) : tn;
      int vn = idxL[gu * TT + taun];     // LDS read; no global idx chain
      f32x4 acc[NRT][2];
#pragma unroll
      for (int rt = 0; rt < NRT; ++rt)
#pragma unroll
        for (int c2 = 0; c2 < 2; ++c2) {
          f32x4 z = {0.f, 0.f, 0.f, 0.f};
          acc[rt][c2] = z;
        }
#pragma unroll
      for (int ks = 0; ks < 8; ++ks) {
        short8 afr[NRT];
#pragma unroll
        for (int rt = 0; rt < NRT; ++rt)
          afr[rt] = *(const short8*)&ash[(rt * 16 + (lane & 15)) * ASTR + ks * 32 + ((lane >> 4) << 3)];
#pragma unroll
        for (int rt = 0; rt < NRT; ++rt)
#pragma unroll
          for (int c2 = 0; c2 < 2; ++c2)
            acc[rt][c2] = __builtin_amdgcn_mfma_f32_16x16x32_bf16(
                afr[rt], bfr[ks][c2], acc[rt][c2], 0, 0, 0);
      }
      // dependent x(t+1) load — with LDS-only barriers its latency spans
      // into the NEXT phase (drains at use, not at the barrier)
      if (MODE == 0) {
        xq = *(const float4*)&srcf[(size_t)vn * 128 + gk0];
      } else {
        bool keep = (taun < gfe) && (vn >= 0) && (vn < gun);
        xs = keep ? src16[(size_t)min(vn + goff, NUNITS - 1) * 128 + gk0] : (unsigned short)0;
      }
      // preacts -> LDS gates (C-layout: col=lane&15, row=quad*4+reg)
#pragma unroll
      for (int rt = 0; rt < NRT; ++rt)
#pragma unroll
        for (int c2 = 0; c2 < 2; ++c2) {
          int g = wv * 32 + c2 * 16 + (lane & 15);
#pragma unroll
          for (int r = 0; r < 4; ++r) {
            int u = rt * 16 + ((lane >> 4) << 2) + r;
            gates[u * GSTR + g] = acc[rt][c2][r];
          }
        }
    }
    barrier_lds();   // gates ready; A-tile reads done (LDS-only drain)

    // ===== PW phase (wave-uniform skip; NO dead-step stores) =====
#pragma unroll
    for (int i = 0; i < NU; ++i) {
      int u = ug * NU + i;
      int n = n0 + u;
      int L = ulen[i];
      if (t < L) {
        if (MODE == 0) {
          float2 g0 = *(const float2*)&gates[u * GSTR + j2];
          float2 g1 = *(const float2*)&gates[u * GSTR + 128 + j2];
          float2 g2 = *(const float2*)&gates[u * GSTR + 256 + j2];
          float2 g3 = *(const float2*)&gates[u * GSTR + 384 + j2];
          float i0 = sigf(g0.x + b2[0].x), i1 = sigf(g0.y + b2[0].y);
          float f0 = sigf(g1.x + b2[1].x), f1 = sigf(g1.y + b2[1].y);
          float c0 = tanhfast(g2.x + b2[2].x), c1 = tanhfast(g2.y + b2[2].y);
          float o0 = sigf(g3.x + b2[3].x), o1 = sigf(g3.y + b2[3].y);
          float cA = f0 * cst0[i] + i0 * c0;
          float cB = f1 * cst1[i] + i1 * c1;
          cst0[i] = cA; cst1[i] = cB;
          unsigned hp = pack_bf(o0 * tanhfast(cA), o1 * tanhfast(cB));
          *(unsigned*)&ash[u * ASTR + 128 + j2] = hp;
          if (dir == 0) *(unsigned*)&outF[((size_t)t * NN + n) * 128 + j2] = hp;
          else          *(unsigned*)&outB[((size_t)(L - 1 - t) * NN + n) * 128 + j2] = hp;
        } else {
          float p0 = gates[u * GSTR + j2]       + b2[0].x;
          float p1 = gates[u * GSTR + 128 + j2] + b2[1].x;
          float p2 = gates[u * GSTR + 256 + j2] + b2[2].x;
          float p3 = gates[u * GSTR + 384 + j2] + b2[3].x;
          float ig = sigf(p0), fg = sigf(p1), gg = tanhfast(p2), og = sigf(p3);
          float c = fg * cst0[i] + ig * gg;
          cst0[i] = c;
          unsigned short hb = f2bf(og * tanhfast(c));
          ash[u * ASTR + 128 + j2] = hb;
          if (dir == 0) outF[((size_t)t * NN + n) * 128 + j2] = hb;
          else          outB[((size_t)(L - 1 - t) * NN + n) * 128 + j2] = hb;
        }
      }
      // t >= L: nothing — downstream GEMMs mask rows t >= len.
    }
    // x(t+1) into A-tile (prefetched during MFMA phase)
    if (t + 1 < TT) {
      if (MODE == 0) {
        short4x x4;
        x4[0] = (short)f2bf(xq.x); x4[1] = (short)f2bf(xq.y);
        x4[2] = (short)f2bf(xq.z); x4[3] = (short)f2bf(xq.w);
        *(short4x*)&ash[gu * ASTR + gk0] = x4;
      } else {
        ash[gu * ASTR + gk0] = xs;
      }
    }
    barrier_lds();   // h(t) + x(t+1) visible (LDS-only drain)
  }
}

// ---------------------------------------------------------------------------
// MFMA GEMM: rows x 128, K=256, A = bf16 [INf|INb] from global, B resident.
// BOTH epilogues mask rows t >= lens[n] (A-frag zero -> OUT = bias).
// EPI 0: f32 store (final output).  EPI 1: bf16 OUT + fused LN/tanh/attn.
// ---------------------------------------------------------------------------
template <int EPI>
__global__ __launch_bounds__(256) void gemm_mfma(
    const unsigned short* __restrict__ INf, const unsigned short* __restrict__ INb,
    const int* __restrict__ lens,
    const unsigned short* __restrict__ Bfrag, const float* __restrict__ bias,
    void* __restrict__ OUTv, float* __restrict__ scores,
    const float* __restrict__ lng, const float* __restrict__ lnb,
    const float* __restrict__ attw, const float* __restrict__ attb,
    const int* __restrict__ units, int Nn)
{
  constexpr int OSTR = 132;
  __shared__ float outs[64 * OSTR];
  __shared__ float red1[256];
  __shared__ float red2[256];
  __shared__ float rowm[64], rowr[64];
  __shared__ float awsh[128], lgsh[128], lbsh[128];

  int tid = threadIdx.x, lane = tid & 63, wv = tid >> 6;
  int row0 = blockIdx.x * 64;
  int t = row0 / Nn, n0 = row0 % Nn;   // 64-row blocks never straddle t

  if (EPI == 1 && tid < 128) {
    awsh[tid] = attw[tid]; lgsh[tid] = lng[tid]; lbsh[tid] = lnb[tid];
  }

  short8 bfr[8][2];
#pragma unroll
  for (int ks = 0; ks < 8; ++ks)
#pragma unroll
    for (int c2 = 0; c2 < 2; ++c2) {
      int ct = wv * 2 + c2;
      bfr[ks][c2] = *(const short8*)&Bfrag[(((ct * 8 + ks) * 64) + lane) * 8];
    }

  int rb = lane & 15;
  int koq = (lane >> 4) << 3;
  bool val[4];
#pragma unroll
  for (int rt = 0; rt < 4; ++rt)
    val[rt] = (t < lens[n0 + rt * 16 + rb]);

  f32x4 acc[4][2];
#pragma unroll
  for (int rt = 0; rt < 4; ++rt)
#pragma unroll
    for (int c2 = 0; c2 < 2; ++c2) {
      f32x4 z = {0.f, 0.f, 0.f, 0.f};
      acc[rt][c2] = z;
    }

#pragma unroll
  for (int ks = 0; ks < 8; ++ks) {
    const unsigned short* P = (ks < 4) ? INf : INb;
    int koff = (ks & 3) * 32 + koq;
#pragma unroll
    for (int rt = 0; rt < 4; ++rt) {
      short8 a = {0, 0, 0, 0, 0, 0, 0, 0};
      if (val[rt])
        a = *(const short8*)&P[((size_t)(row0 + rt * 16 + rb)) * 128 + koff];
#pragma unroll
      for (int c2 = 0; c2 < 2; ++c2)
        acc[rt][c2] = __builtin_amdgcn_mfma_f32_16x16x32_bf16(
            a, bfr[ks][c2], acc[rt][c2], 0, 0, 0);
    }
  }

  float bc[2];
#pragma unroll
  for (int c2 = 0; c2 < 2; ++c2) bc[c2] = bias[wv * 32 + c2 * 16 + rb];
#pragma unroll
  for (int rt = 0; rt < 4; ++rt)
#pragma unroll
    for (int c2 = 0; c2 < 2; ++c2) {
      int col = wv * 32 + c2 * 16 + rb;
      int ub  = rt * 16 + ((lane >> 4) << 2);
#pragma unroll
      for (int r = 0; r < 4; ++r)
        outs[(ub + r) * OSTR + col] = acc[rt][c2][r] + bc[c2];
    }
  __syncthreads();

  int row = tid >> 2, seg = tid & 3;
  const float* rp = &outs[row * OSTR + seg * 32];
  size_t go = ((size_t)(row0 + row)) * 128 + seg * 32;

  if (EPI == 0) {
    float* OUT = (float*)OUTv;
#pragma unroll
    for (int x = 0; x < 8; ++x)
      *(f32x4*)&OUT[go + x * 4] = *(const f32x4*)&rp[x * 4];
  } else {
    unsigned short* OUT = (unsigned short*)OUTv;
    f32x4 v[8];
    float s = 0.f, s2 = 0.f;
#pragma unroll
    for (int x = 0; x < 8; ++x) {
      v[x] = *(const f32x4*)&rp[x * 4];
#pragma unroll
      for (int c = 0; c < 4; ++c) { s += v[x][c]; s2 += v[x][c] * v[x][c]; }
    }
    red1[tid] = s; red2[tid] = s2;
    __syncthreads();
    if (tid < 64) {
      float a = red1[tid * 4] + red1[tid * 4 + 1] + red1[tid * 4 + 2] + red1[tid * 4 + 3];
      float b = red2[tid * 4] + red2[tid * 4 + 1] + red2[tid * 4 + 2] + red2[tid * 4 + 3];
      float m = a * (1.f / 128.f);
      float var = b * (1.f / 128.f) - m * m;
      rowm[tid] = m;
      rowr[tid] = rsqrtf(var + 1e-5f);
    }
    __syncthreads();
    float m = rowm[row], rs = rowr[row];
    float sp = 0.f;
#pragma unroll
    for (int x = 0; x < 8; ++x) {
      short4x pv;
#pragma unroll
      for (int c = 0; c < 4; ++c) {
        int col = seg * 32 + x * 4 + c;
        float q = tanhfast((v[x][c] - m) * rs * lgsh[col] + lbsh[col]);
        sp += q * awsh[col];
        pv[c] = (short)f2bf(v[x][c]);
      }
      *(short4x*)&OUT[go + x * 4] = pv;   // bf16 intermediate (8B store)
    }
    red1[tid] = sp;
    __syncthreads();
    if (tid < 64) {
      float s3 = red1[tid * 4] + red1[tid * 4 + 1] + red1[tid * 4 + 2] + red1[tid * 4 + 3]
               + attb[0];
      int n = n0 + tid;
      if (units[t * NUNITS + n] == 0) s3 = -1e9f;
      scores[t * NUNITS + n] = s3;
    }
  }
}

// ---------------------------------------------------------------------------
// Softmax over T=16 + attention-weighted pooling -> tok_feat (bf16).
// ROUND-12 delta (only change vs r9): vectorized — thread handles 4
// e-columns via uint2 (8B) loads/stores; 4 units per 128-thread block;
// grid 4096 -> 1024. Per-element accumulation order unchanged ->
// bit-identical results.
// ---------------------------------------------------------------------------
__global__ __launch_bounds__(128) void softmax_feat_kernel(
    const float* __restrict__ scores, const unsigned short* __restrict__ out_lin,
    unsigned short* __restrict__ tok_feat)
{
  int tid = threadIdx.x;
  int n  = blockIdx.x * 4 + (tid >> 5);
  int e0 = (tid & 31) * 4;
  float s[T_TOKN];
  float m = -1e30f;
#pragma unroll
  for (int t = 0; t < T_TOKN; ++t) { s[t] = scores[t * NUNITS + n]; m = fmaxf(m, s[t]); }
  float sum = 0.f;
#pragma unroll
  for (int t = 0; t < T_TOKN; ++t) { s[t] = expf(s[t] - m); sum += s[t]; }
  float inv = 1.f / sum;
  float a0 = 0.f, a1 = 0.f, a2 = 0.f, a3 = 0.f;
#pragma unroll
  for (int t = 0; t < T_TOKN; ++t) {
    float w = s[t] * inv;
    uint2 v = *(const uint2*)&out_lin[((size_t)t * NUNITS + n) * 128 + e0];
    a0 += w * bf2f((unsigned short)(v.x & 0xffffu));
    a1 += w * bf2f((unsigned short)(v.x >> 16));
    a2 += w * bf2f((unsigned short)(v.y & 0xffffu));
    a3 += w * bf2f((unsigned short)(v.y >> 16));
  }
  uint2 o;
  o.x = (unsigned)f2bf(a0) | ((unsigned)f2bf(a1) << 16);
  o.y = (unsigned)f2bf(a2) | ((unsigned)f2bf(a3) << 16);
  *(uint2*)&tok_feat[(size_t)n * 128 + e0] = o;
}

// ---------------------------------------------------------------------------
extern "C" void kernel_launch(void* const* d_in, const int* in_sizes, int n_in,
                              void* d_out, int out_size, void* d_ws, size_t ws_size,
                              hipStream_t stream)
{
  const int*   units = (const int*)d_in[0];
  const int*   paths = (const int*)d_in[1];
  const int*   upd   = (const int*)d_in[2];
  const int*   ppd   = (const int*)d_in[3];
  const float* emb   = (const float*)d_in[4];
  const float* tWif  = (const float*)d_in[5];
  const float* tWhf  = (const float*)d_in[6];
  const float* tbf   = (const float*)d_in[7];
  const float* tWib  = (const float*)d_in[8];
  const float* tWhb  = (const float*)d_in[9];
  const float* tbb   = (const float*)d_in[10];
  const float* linW  = (const float*)d_in[11];
  const float* linb  = (const float*)d_in[12];
  const float* lng   = (const float*)d_in[13];
  const float* lnb   = (const float*)d_in[14];
  const float* attw  = (const float*)d_in[15];
  const float* attb  = (const float*)d_in[16];
  const float* pWif  = (const float*)d_in[17];
  const float* pWhf  = (const float*)d_in[18];
  const float* pbf   = (const float*)d_in[19];
  const float* pWib  = (const float*)d_in[20];
  const float* pWhb  = (const float*)d_in[21];
  const float* pbb   = (const float*)d_in[22];
  const float* ulW   = (const float*)d_in[23];
  const float* ulb   = (const float*)d_in[24];

  float* ws = (float*)d_ws;
  int*   ip = (int*)(ws + OFF_INT);
  if (ws_size < WS_FLOATS * sizeof(float)) return;

  unsigned short* wfrag   = (unsigned short*)(ws + OFF_WFRAG);
  unsigned short* linfrag = (unsigned short*)(ws + OFF_LINFRAG);
  unsigned short* ulfrag  = linfrag + 32768;
  unsigned short* OUTF  = (unsigned short*)(ws + OFF_OUTF);
  unsigned short* OUTB  = (unsigned short*)(ws + OFF_OUTB);
  unsigned short* POUTF = (unsigned short*)(ws + OFF_POUTF);
  unsigned short* POUTB = (unsigned short*)(ws + OFF_POUTB);
  unsigned short* TOKF16 = (unsigned short*)(ws + OFF_TOKFEAT);

  prep_kernel<<<308, 256, 0, stream>>>(tWif, tWhf, tWib, tWhb,
                                       pWif, pWhf, pWib, pWhb,
                                       linW, ulW, units, paths, upd, ppd,
                                       ws, ip);

  lstm_kernel<0><<<dim3(128, 2), 1024, 0, stream>>>(
      wfrag, tbf, tbb, (const void*)emb, units, ip /*tok_len*/,
      nullptr, nullptr, nullptr, OUTF, OUTB);

  gemm_mfma<1><<<1024, 256, 0, stream>>>(
      OUTF, OUTB, ip /*tok_len*/, linfrag, linb,
      (void*)(ws + OFF_OUTLIN), ws + OFF_SCORES, lng, lnb, attw, attb, units, NUNITS);

  softmax_feat_kernel<<<1024, 128, 0, stream>>>(
      ws + OFF_SCORES, (const unsigned short*)(ws + OFF_OUTLIN), TOKF16);

  lstm_kernel<1><<<dim3(128, 2), 1024, 0, stream>>>(
      wfrag, pbf, pbb, (const void*)TOKF16, paths, ip + 5120 /*p_len*/,
      ip + 4096 /*fe*/, ip + 6144 /*off_p*/, ip + 7168 /*un_p*/,
      POUTF, POUTB);

  gemm_mfma<0><<<512, 256, 0, stream>>>(
      POUTF, POUTB, ip + 5120 /*p_len*/, ulfrag, ulb,
      (void*)d_out, nullptr, nullptr, nullptr, nullptr, nullptr, nullptr, NPATHS);
}

// Round 13
// 298.150 us; speedup vs baseline: 1.1751x; 1.0002x over previous
//
#include <hip/hip_runtime.h>
#include <cstdint>
#include <cstddef>

// Problem constants
#define T_TOKN 16
#define NUNITS 4096
#define LPATH  32
#define NPATHS 1024
#define BNUM   8

typedef __attribute__((ext_vector_type(8))) short short8;   // 8 bf16 in 4 VGPRs
typedef __attribute__((ext_vector_type(4))) short short4x;  // 4 bf16 in 2 VGPRs
typedef __attribute__((ext_vector_type(4))) float f32x4;    // MFMA accumulator

// ws float offsets
enum : size_t {
  OFF_WFRAG   = 0,                        // 524288 ushort: lstm W frags [tf|tb|pf|pb]
  OFF_LINFRAG = 262144,                   // 65536 ushort: lin/ul B-frags
  OFF_OUTF    = 294912,                   // token fwd h, bf16 16x4096x128
  OFF_OUTB    = OFF_OUTF + 4194304,       // token bwd h (time-realigned), bf16
  OFF_OUTLIN  = OFF_OUTB + 4194304,       // bf16 16x4096x128 (gemm1 out; ALSO
                                          // overlaid emb16 4MB written by prep,
                                          // consumed by lstm0, dead before gemm1)
  OFF_SCORES  = OFF_OUTLIN + 8388608,     // f32 16x4096
  OFF_TOKFEAT = OFF_SCORES + 65536,       // bf16 4096x128 (intermediate only)
  OFF_POUTF   = OFF_TOKFEAT + 524288,     // path fwd h, bf16 32x1024x128
  OFF_POUTB   = OFF_POUTF + 2097152,
  OFF_INT     = OFF_POUTB + 2097152,      // ints: tok_len 4096 | fe 1024 | p_len 1024 | off_p 1024 | un_p 1024
  WS_FLOATS   = OFF_INT + 8192
};

static __device__ __forceinline__ unsigned short f2bf(float f) {
  union { float f; unsigned u; } v; v.f = f;
  unsigned r = v.u + 0x7fffu + ((v.u >> 16) & 1u);
  return (unsigned short)(r >> 16);
}
static __device__ __forceinline__ float bf2f(unsigned short u) {
  union { unsigned u; float f; } v; v.u = ((unsigned)u) << 16;
  return v.f;
}
static __device__ __forceinline__ unsigned pack_bf(float a, float b) {
  return (unsigned)f2bf(a) | ((unsigned)f2bf(b) << 16);
}
static __device__ __forceinline__ float sigf(float x)      { return 1.f / (1.f + __expf(-x)); }
static __device__ __forceinline__ float tanhfast(float x)  { return 2.f / (1.f + __expf(-2.f * x)) - 1.f; }

// LDS-only barrier (r9-verified): waits LDS ops but not global loads/stores.
static __device__ __forceinline__ void barrier_lds() {
  asm volatile("s_waitcnt lgkmcnt(0)\n\ts_barrier" ::: "memory");
}

// ---------------------------------------------------------------------------
// prep (coalesced, r6-verified) + ROUND-13: emb -> bf16 (overlaid on the
// OUTLIN region; same f2bf rounding the lstm gather used to apply per-load,
// so bit-identical downstream).
// ---------------------------------------------------------------------------
__global__ void prep_kernel(
    const float* __restrict__ tWif, const float* __restrict__ tWhf,
    const float* __restrict__ tWib, const float* __restrict__ tWhb,
    const float* __restrict__ pWif, const float* __restrict__ pWhf,
    const float* __restrict__ pWib, const float* __restrict__ pWhb,
    const float* __restrict__ linW, const float* __restrict__ ulW,
    const float* __restrict__ emb,
    const int* __restrict__ units, const int* __restrict__ paths,
    const int* __restrict__ upd, const int* __restrict__ ppd,
    float* __restrict__ ws, int* __restrict__ ip)
{
  int idx = blockIdx.x * 256 + threadIdx.x;
  if (idx < 65536) {
    unsigned short* wf = (unsigned short*)(ws + OFF_WFRAG);
    int k8 = idx & 31, g = (idx >> 5) & 511, mat = idx >> 14;
    const float* Wi; const float* Wh;
    switch (mat) {
      case 0: Wi = tWif; Wh = tWhf; break;
      case 1: Wi = tWib; Wh = tWhb; break;
      case 2: Wi = pWif; Wh = pWhf; break;
      default: Wi = pWib; Wh = pWhb; break;
    }
    int kb = k8 << 3;
    const float* sp = (kb < 128) ? (Wi + g * 128 + kb) : (Wh + g * 128 + (kb - 128));
    float4 a = *(const float4*)sp;
    float4 b = *(const float4*)(sp + 4);
    int wvp = g >> 6, ct = (g >> 4) & 3, cl = g & 15;
    int ks = k8 >> 2, quad = k8 & 3;
    size_t base = ((size_t)mat << 17) +
                  (size_t)(((((wvp * 8 + ks) * 4 + ct) * 64) + quad * 16 + cl) << 3);
    short8 o;
    o[0] = (short)f2bf(a.x); o[1] = (short)f2bf(a.y);
    o[2] = (short)f2bf(a.z); o[3] = (short)f2bf(a.w);
    o[4] = (short)f2bf(b.x); o[5] = (short)f2bf(b.y);
    o[6] = (short)f2bf(b.z); o[7] = (short)f2bf(b.w);
    *(short8*)&wf[base] = o;
  } else if (idx < 65536 + 8192) {
    unsigned short* lf = (unsigned short*)(ws + OFF_LINFRAG);
    int j = idx - 65536;
    int k8 = j & 31, e = (j >> 5) & 127, mat = j >> 12;
    const float* W = mat ? ulW : linW;
    int kb = k8 << 3;
    const float* sp = W + e * 256 + kb;
    float4 a = *(const float4*)sp;
    float4 b = *(const float4*)(sp + 4);
    int ct = e >> 4, cl = e & 15;
    int ks = k8 >> 2, quad = k8 & 3;
    size_t base = ((size_t)mat << 15) +
                  (size_t)((((ct * 8 + ks) * 64) + quad * 16 + cl) << 3);
    short8 o;
    o[0] = (short)f2bf(a.x); o[1] = (short)f2bf(a.y);
    o[2] = (short)f2bf(a.z); o[3] = (short)f2bf(a.w);
    o[4] = (short)f2bf(b.x); o[5] = (short)f2bf(b.y);
    o[6] = (short)f2bf(b.z); o[7] = (short)f2bf(b.w);
    *(short8*)&lf[base] = o;
  } else if (idx < 73728 + 4096) {
    int n = idx - 73728;
    int len = T_TOKN;
    for (int t = 0; t < T_TOKN; ++t)
      if (units[t * NUNITS + n] == 0) { len = t; break; }
    ip[n] = len;                                   // tok_len
  } else if (idx < 77824 + 1024) {
    int p = idx - 77824;
    int* fe_a  = ip + 4096;
    int* p_len = ip + 5120;
    int* off_p = ip + 6144;
    int* un_p  = ip + 7168;
    int cum = 0; int d = BNUM - 1;
    for (int dd = 0; dd < BNUM; ++dd) {
      int c2 = cum + ppd[dd];
      if (p < c2) { d = dd; break; }
      cum = c2;
    }
    int off = 0;
    for (int dd = 0; dd < d; ++dd) off += upd[dd];
    int un = upd[d];
    off_p[p] = off; un_p[p] = un;
    int f = LPATH;
    for (int t = 0; t < LPATH; ++t)
      if (paths[t * NPATHS + p] == -1) { f = t; break; }
    fe_a[p] = f;
    int pl = LPATH;
    for (int t = 0; t < LPATH; ++t) {
      int v = paths[t * NPATHS + p];
      if ((t >= f) || (v < 0) || (v > un)) { pl = t; break; }
    }
    p_len[p] = pl;
  } else if (idx < 78848 + 262144) {
    // ---- emb -> bf16 (8 elems/thread), overlaid on OUTLIN region ----
    int j = idx - 78848;
    unsigned short* e16 = (unsigned short*)(ws + OFF_OUTLIN);
    const float* sp = emb + (size_t)j * 8;
    float4 a = *(const float4*)sp;
    float4 b = *(const float4*)(sp + 4);
    short8 o;
    o[0] = (short)f2bf(a.x); o[1] = (short)f2bf(a.y);
    o[2] = (short)f2bf(a.z); o[3] = (short)f2bf(a.w);
    o[4] = (short)f2bf(b.x); o[5] = (short)f2bf(b.y);
    o[6] = (short)f2bf(b.z); o[7] = (short)f2bf(b.w);
    *(short8*)&e16[(size_t)j * 8] = o;
  }
}

// ---------------------------------------------------------------------------
// MFMA BiLSTM, 16-wave blocks, resident B (32 gate-cols/wave, 64 VGPR/lane).
// = r12 core (known-good) + ROUND-13 deltas (both bit-exact):
//  (1) idxL is now FULLY RESOLVED at preamble: dir-aware time reversal and
//      (MODE 1) keep-mask + offset + clamp are baked into the table
//      (entry = final src row index, or -1 = zero). Hot-loop per-step
//      address work collapses to one LDS read (+ sign test in MODE 1).
//  (2) MODE 0 x-source is bf16 (emb16 from prep): gather is an 8B ushort4
//      load stored directly to LDS — no per-step f2bf/pack.
// Keeps: wave-uniform dead-step skip, no dead-step stores, r0 phase order,
// bf16 OUTLIN/tok_feat, LDS-only in-loop barriers.
// MODE 0: token (M=32, MR=32). MODE 1: path (M=8, MR=16, scalar pointwise).
// ---------------------------------------------------------------------------
template <int MODE>
__global__ __launch_bounds__(1024, 4) void lstm_kernel(
    const unsigned short* __restrict__ wfragAll,
    const float* __restrict__ biasF, const float* __restrict__ biasB,
    const unsigned short* __restrict__ src16,  // emb16 or tok_feat (bf16)
    const int* __restrict__ idxsrc,      // units or paths
    const int* __restrict__ lens,        // tok_len or p_len
    const int* __restrict__ fe_a, const int* __restrict__ off_p, const int* __restrict__ un_p,
    unsigned short* __restrict__ outF, unsigned short* __restrict__ outB)
{
  constexpr int NN   = MODE ? NPATHS : NUNITS;
  constexpr int TT   = MODE ? LPATH : T_TOKN;
  constexpr int M    = MODE ? 8 : 32;     // real sequences per block
  constexpr int MR   = MODE ? 16 : 32;    // MFMA tile rows
  constexpr int NRT  = MR / 16;
  constexpr int ASTR = 264;               // A-tile row stride (ushorts)
  constexpr int GSTR = 514;               // gates row stride (f32)

  __shared__ unsigned short ash[MR * ASTR];  // [u][0:128)=x  [u][128:256)=h
  __shared__ float gates[MR * GSTR];
  __shared__ int   idxL[M * TT];             // RESOLVED index table

  int tid  = threadIdx.x;
  int dir  = blockIdx.y;
  int n0   = blockIdx.x * M;
  int lane = tid & 63, wv = tid >> 6;       // wv in [0,16)

  // ---- resident B fragments: wave wv covers gates [wv*32, wv*32+32) ----
  const unsigned short* wbase =
      wfragAll + (size_t)((MODE ? 2 : 0) + dir) * 131072;
  int wv8 = wv >> 1;
  short8 bfr[8][2];
#pragma unroll
  for (int ks = 0; ks < 8; ++ks)
#pragma unroll
    for (int c2 = 0; c2 < 2; ++c2) {
      int ct = ((wv & 1) << 1) | c2;
      bfr[ks][c2] = *(const short8*)&wbase[((((wv8 * 8 + ks) * 4 + ct) * 64) + lane) * 8];
    }

  // ---- zero LDS (h region; MODE 1: whole tile incl dummy rows) ----
  if (MODE == 0) {
    for (int i = tid; i < MR * 128; i += 1024)
      ash[(i >> 7) * ASTR + 128 + (i & 127)] = 0;
  } else {
    for (int i = tid; i < MR * ASTR; i += 1024) ash[i] = 0;
  }
  // ---- preload + RESOLVE idx table: idxL[u*TT + t] = final src row / -1 ----
  for (int i = tid; i < M * TT; i += 1024) {
    int u = i / TT, tt = i - u * TT;       // TT power of 2 -> shifts
    int n = n0 + u;
    int L = lens[n];
    int tau = dir ? min(max(L - 1 - tt, 0), TT - 1) : tt;
    int v = idxsrc[tau * NN + n];
    if constexpr (MODE == 0) {
      idxL[i] = v;                         // token id, always valid
    } else {
      bool keep = (tau < fe_a[n]) && (v >= 0) && (v < un_p[n]);
      idxL[i] = keep ? min(v + off_p[n], NUNITS - 1) : -1;
    }
  }

  // ---- pointwise thread state ----
  const float* bcp = dir ? biasB : biasF;
  // MODE 0: thread = wave's unit pair x j pair.  MODE 1: 1 unit x 1 j.
  int j2 = MODE ? (tid & 127) : ((tid & 63) * 2);
  int ug = MODE ? (tid >> 7)  : (tid >> 6);
  float2 b2[4];
#pragma unroll
  for (int q = 0; q < 4; ++q) {
    if (MODE == 0) b2[q] = *(const float2*)&bcp[q * 128 + j2];
    else           b2[q] = make_float2(bcp[q * 128 + j2], 0.f);
  }
  constexpr int NU = MODE ? 1 : 2;          // units per pointwise thread
  float cst0[NU], cst1[NU];
  int   ulen[NU];
#pragma unroll
  for (int i = 0; i < NU; ++i) {
    cst0[i] = 0.f; cst1[i] = 0.f;
    ulen[i] = lens[n0 + ug * NU + i];
  }

  // ---- gather thread state ----
  int gu, gk0;
  if (MODE == 0) { gu = tid >> 5; gk0 = (tid & 31) * 4; }   // 32 rows x 32 thr x 8B
  else           { gu = tid >> 7; gk0 = tid & 127; }        // 8 rows x 128 thr x u16

  short4x xq4; unsigned short xs;
  __syncthreads();   // zeros + idxL visible (full barrier: preamble only)

  // ---- preamble: load + write x(0) ----
  {
    int v = idxL[gu * TT + 0];
    if constexpr (MODE == 0) {
      xq4 = *(const short4x*)&src16[(size_t)v * 128 + gk0];
      *(short4x*)&ash[gu * ASTR + gk0] = xq4;
    } else {
      xs = (v >= 0) ? src16[(size_t)v * 128 + gk0] : (unsigned short)0;
      ash[gu * ASTR + gk0] = xs;
    }
  }
  __syncthreads();   // x(0) visible

#pragma unroll 1
  for (int t = 0; t < TT; ++t) {
    // ===== MFMA phase (r0 ordering) =====
    {
      int tn = (t + 1 < TT) ? t + 1 : t;
      int vn = idxL[gu * TT + tn];       // resolved: LDS read only
      f32x4 acc[NRT][2];
#pragma unroll
      for (int rt = 0; rt < NRT; ++rt)
#pragma unroll
        for (int c2 = 0; c2 < 2; ++c2) {
          f32x4 z = {0.f, 0.f, 0.f, 0.f};
          acc[rt][c2] = z;
        }
#pragma unroll
      for (int ks = 0; ks < 8; ++ks) {
        short8 afr[NRT];
#pragma unroll
        for (int rt = 0; rt < NRT; ++rt)
          afr[rt] = *(const short8*)&ash[(rt * 16 + (lane & 15)) * ASTR + ks * 32 + ((lane >> 4) << 3)];
#pragma unroll
        for (int rt = 0; rt < NRT; ++rt)
#pragma unroll
          for (int c2 = 0; c2 < 2; ++c2)
            acc[rt][c2] = __builtin_amdgcn_mfma_f32_16x16x32_bf16(
                afr[rt], bfr[ks][c2], acc[rt][c2], 0, 0, 0);
      }
      // x(t+1) load — latency spans into the next phase (LDS-only barriers)
      if constexpr (MODE == 0) {
        xq4 = *(const short4x*)&src16[(size_t)vn * 128 + gk0];
      } else {
        xs = (vn >= 0) ? src16[(size_t)vn * 128 + gk0] : (unsigned short)0;
      }
      // preacts -> LDS gates (C-layout: col=lane&15, row=quad*4+reg)
#pragma unroll
      for (int rt = 0; rt < NRT; ++rt)
#pragma unroll
        for (int c2 = 0; c2 < 2; ++c2) {
          int g = wv * 32 + c2 * 16 + (lane & 15);
#pragma unroll
          for (int r = 0; r < 4; ++r) {
            int u = rt * 16 + ((lane >> 4) << 2) + r;
            gates[u * GSTR + g] = acc[rt][c2][r];
          }
        }
    }
    barrier_lds();   // gates ready; A-tile reads done (LDS-only drain)

    // ===== PW phase (wave-uniform skip; NO dead-step stores) =====
#pragma unroll
    for (int i = 0; i < NU; ++i) {
      int u = ug * NU + i;
      int n = n0 + u;
      int L = ulen[i];
      if (t < L) {
        if (MODE == 0) {
          float2 g0 = *(const float2*)&gates[u * GSTR + j2];
          float2 g1 = *(const float2*)&gates[u * GSTR + 128 + j2];
          float2 g2 = *(const float2*)&gates[u * GSTR + 256 + j2];
          float2 g3 = *(const float2*)&gates[u * GSTR + 384 + j2];
          float i0 = sigf(g0.x + b2[0].x), i1 = sigf(g0.y + b2[0].y);
          float f0 = sigf(g1.x + b2[1].x), f1 = sigf(g1.y + b2[1].y);
          float c0 = tanhfast(g2.x + b2[2].x), c1 = tanhfast(g2.y + b2[2].y);
          float o0 = sigf(g3.x + b2[3].x), o1 = sigf(g3.y + b2[3].y);
          float cA = f0 * cst0[i] + i0 * c0;
          float cB = f1 * cst1[i] + i1 * c1;
          cst0[i] = cA; cst1[i] = cB;
          unsigned hp = pack_bf(o0 * tanhfast(cA), o1 * tanhfast(cB));
          *(unsigned*)&ash[u * ASTR + 128 + j2] = hp;
          if (dir == 0) *(unsigned*)&outF[((size_t)t * NN + n) * 128 + j2] = hp;
          else          *(unsigned*)&outB[((size_t)(L - 1 - t) * NN + n) * 128 + j2] = hp;
        } else {
          float p0 = gates[u * GSTR + j2]       + b2[0].x;
          float p1 = gates[u * GSTR + 128 + j2] + b2[1].x;
          float p2 = gates[u * GSTR + 256 + j2] + b2[2].x;
          float p3 = gates[u * GSTR + 384 + j2] + b2[3].x;
          float ig = sigf(p0), fg = sigf(p1), gg = tanhfast(p2), og = sigf(p3);
          float c = fg * cst0[i] + ig * gg;
          cst0[i] = c;
          unsigned short hb = f2bf(og * tanhfast(c));
          ash[u * ASTR + 128 + j2] = hb;
          if (dir == 0) outF[((size_t)t * NN + n) * 128 + j2] = hb;
          else          outB[((size_t)(L - 1 - t) * NN + n) * 128 + j2] = hb;
        }
      }
      // t >= L: nothing — downstream GEMMs mask rows t >= len.
    }
    // x(t+1) into A-tile (prefetched during MFMA phase)
    if (t + 1 < TT) {
      if constexpr (MODE == 0) {
        *(short4x*)&ash[gu * ASTR + gk0] = xq4;
      } else {
        ash[gu * ASTR + gk0] = xs;
      }
    }
    barrier_lds();   // h(t) + x(t+1) visible (LDS-only drain)
  }
}

// ---------------------------------------------------------------------------
// MFMA GEMM: rows x 128, K=256, A = bf16 [INf|INb] from global, B resident.
// BOTH epilogues mask rows t >= lens[n] (A-frag zero -> OUT = bias).
// EPI 0: f32 store (final output).  EPI 1: bf16 OUT + fused LN/tanh/attn.
// ---------------------------------------------------------------------------
template <int EPI>
__global__ __launch_bounds__(256) void gemm_mfma(
    const unsigned short* __restrict__ INf, const unsigned short* __restrict__ INb,
    const int* __restrict__ lens,
    const unsigned short* __restrict__ Bfrag, const float* __restrict__ bias,
    void* __restrict__ OUTv, float* __restrict__ scores,
    const float* __restrict__ lng, const float* __restrict__ lnb,
    const float* __restrict__ attw, const float* __restrict__ attb,
    const int* __restrict__ units, int Nn)
{
  constexpr int OSTR = 132;
  __shared__ float outs[64 * OSTR];
  __shared__ float red1[256];
  __shared__ float red2[256];
  __shared__ float rowm[64], rowr[64];
  __shared__ float awsh[128], lgsh[128], lbsh[128];

  int tid = threadIdx.x, lane = tid & 63, wv = tid >> 6;
  int row0 = blockIdx.x * 64;
  int t = row0 / Nn, n0 = row0 % Nn;   // 64-row blocks never straddle t

  if (EPI == 1 && tid < 128) {
    awsh[tid] = attw[tid]; lgsh[tid] = lng[tid]; lbsh[tid] = lnb[tid];
  }

  short8 bfr[8][2];
#pragma unroll
  for (int ks = 0; ks < 8; ++ks)
#pragma unroll
    for (int c2 = 0; c2 < 2; ++c2) {
      int ct = wv * 2 + c2;
      bfr[ks][c2] = *(const short8*)&Bfrag[(((ct * 8 + ks) * 64) + lane) * 8];
    }

  int rb = lane & 15;
  int koq = (lane >> 4) << 3;
  bool val[4];
#pragma unroll
  for (int rt = 0; rt < 4; ++rt)
    val[rt] = (t < lens[n0 + rt * 16 + rb]);

  f32x4 acc[4][2];
#pragma unroll
  for (int rt = 0; rt < 4; ++rt)
#pragma unroll
    for (int c2 = 0; c2 < 2; ++c2) {
      f32x4 z = {0.f, 0.f, 0.f, 0.f};
      acc[rt][c2] = z;
    }

#pragma unroll
  for (int ks = 0; ks < 8; ++ks) {
    const unsigned short* P = (ks < 4) ? INf : INb;
    int koff = (ks & 3) * 32 + koq;
#pragma unroll
    for (int rt = 0; rt < 4; ++rt) {
      short8 a = {0, 0, 0, 0, 0, 0, 0, 0};
      if (val[rt])
        a = *(const short8*)&P[((size_t)(row0 + rt * 16 + rb)) * 128 + koff];
#pragma unroll
      for (int c2 = 0; c2 < 2; ++c2)
        acc[rt][c2] = __builtin_amdgcn_mfma_f32_16x16x32_bf16(
            a, bfr[ks][c2], acc[rt][c2], 0, 0, 0);
    }
  }

  float bc[2];
#pragma unroll
  for (int c2 = 0; c2 < 2; ++c2) bc[c2] = bias[wv * 32 + c2 * 16 + rb];
#pragma unroll
  for (int rt = 0; rt < 4; ++rt)
#pragma unroll
    for (int c2 = 0; c2 < 2; ++c2) {
      int col = wv * 32 + c2 * 16 + rb;
      int ub  = rt * 16 + ((lane >> 4) << 2);
#pragma unroll
      for (int r = 0; r < 4; ++r)
        outs[(ub + r) * OSTR + col] = acc[rt][c2][r] + bc[c2];
    }
  __syncthreads();

  int row = tid >> 2, seg = tid & 3;
  const float* rp = &outs[row * OSTR + seg * 32];
  size_t go = ((size_t)(row0 + row)) * 128 + seg * 32;

  if (EPI == 0) {
    float* OUT = (float*)OUTv;
#pragma unroll
    for (int x = 0; x < 8; ++x)
      *(f32x4*)&OUT[go + x * 4] = *(const f32x4*)&rp[x * 4];
  } else {
    unsigned short* OUT = (unsigned short*)OUTv;
    f32x4 v[8];
    float s = 0.f, s2 = 0.f;
#pragma unroll
    for (int x = 0; x < 8; ++x) {
      v[x] = *(const f32x4*)&rp[x * 4];
#pragma unroll
      for (int c = 0; c < 4; ++c) { s += v[x][c]; s2 += v[x][c] * v[x][c]; }
    }
    red1[tid] = s; red2[tid] = s2;
    __syncthreads();
    if (tid < 64) {
      float a = red1[tid * 4] + red1[tid * 4 + 1] + red1[tid * 4 + 2] + red1[tid * 4 + 3];
      float b = red2[tid * 4] + red2[tid * 4 + 1] + red2[tid * 4 + 2] + red2[tid * 4 + 3];
      float m = a * (1.f / 128.f);
      float var = b * (1.f / 128.f) - m * m;
      rowm[tid] = m;
      rowr[tid] = rsqrtf(var + 1e-5f);
    }
    __syncthreads();
    float m = rowm[row], rs = rowr[row];
    float sp = 0.f;
#pragma unroll
    for (int x = 0; x < 8; ++x) {
      short4x pv;
#pragma unroll
      for (int c = 0; c < 4; ++c) {
        int col = seg * 32 + x * 4 + c;
        float q = tanhfast((v[x][c] - m) * rs * lgsh[col] + lbsh[col]);
        sp += q * awsh[col];
        pv[c] = (short)f2bf(v[x][c]);
      }
      *(short4x*)&OUT[go + x * 4] = pv;   // bf16 intermediate (8B store)
    }
    red1[tid] = sp;
    __syncthreads();
    if (tid < 64) {
      float s3 = red1[tid * 4] + red1[tid * 4 + 1] + red1[tid * 4 + 2] + red1[tid * 4 + 3]
               + attb[0];
      int n = n0 + tid;
      if (units[t * NUNITS + n] == 0) s3 = -1e9f;
      scores[t * NUNITS + n] = s3;
    }
  }
}

// ---------------------------------------------------------------------------
// Softmax over T=16 + attention-weighted pooling -> tok_feat (bf16).
// r12-vectorized (4 cols/thread via uint2, bit-identical math).
// ---------------------------------------------------------------------------
__global__ __launch_bounds__(128) void softmax_feat_kernel(
    const float* __restrict__ scores, const unsigned short* __restrict__ out_lin,
    unsigned short* __restrict__ tok_feat)
{
  int tid = threadIdx.x;
  int n  = blockIdx.x * 4 + (tid >> 5);
  int e0 = (tid & 31) * 4;
  float s[T_TOKN];
  float m = -1e30f;
#pragma unroll
  for (int t = 0; t < T_TOKN; ++t) { s[t] = scores[t * NUNITS + n]; m = fmaxf(m, s[t]); }
  float sum = 0.f;
#pragma unroll
  for (int t = 0; t < T_TOKN; ++t) { s[t] = expf(s[t] - m); sum += s[t]; }
  float inv = 1.f / sum;
  float a0 = 0.f, a1 = 0.f, a2 = 0.f, a3 = 0.f;
#pragma unroll
  for (int t = 0; t < T_TOKN; ++t) {
    float w = s[t] * inv;
    uint2 v = *(const uint2*)&out_lin[((size_t)t * NUNITS + n) * 128 + e0];
    a0 += w * bf2f((unsigned short)(v.x & 0xffffu));
    a1 += w * bf2f((unsigned short)(v.x >> 16));
    a2 += w * bf2f((unsigned short)(v.y & 0xffffu));
    a3 += w * bf2f((unsigned short)(v.y >> 16));
  }
  uint2 o;
  o.x = (unsigned)f2bf(a0) | ((unsigned)f2bf(a1) << 16);
  o.y = (unsigned)f2bf(a2) | ((unsigned)f2bf(a3) << 16);
  *(uint2*)&tok_feat[(size_t)n * 128 + e0] = o;
}

// ---------------------------------------------------------------------------
extern "C" void kernel_launch(void* const* d_in, const int* in_sizes, int n_in,
                              void* d_out, int out_size, void* d_ws, size_t ws_size,
                              hipStream_t stream)
{
  const int*   units = (const int*)d_in[0];
  const int*   paths = (const int*)d_in[1];
  const int*   upd   = (const int*)d_in[2];
  const int*   ppd   = (const int*)d_in[3];
  const float* emb   = (const float*)d_in[4];
  const float* tWif  = (const float*)d_in[5];
  const float* tWhf  = (const float*)d_in[6];
  const float* tbf   = (const float*)d_in[7];
  const float* tWib  = (const float*)d_in[8];
  const float* tWhb  = (const float*)d_in[9];
  const float* tbb   = (const float*)d_in[10];
  const float* linW  = (const float*)d_in[11];
  const float* linb  = (const float*)d_in[12];
  const float* lng   = (const float*)d_in[13];
  const float* lnb   = (const float*)d_in[14];
  const float* attw  = (const float*)d_in[15];
  const float* attb  = (const float*)d_in[16];
  const float* pWif  = (const float*)d_in[17];
  const float* pWhf  = (const float*)d_in[18];
  const float* pbf   = (const float*)d_in[19];
  const float* pWib  = (const float*)d_in[20];
  const float* pWhb  = (const float*)d_in[21];
  const float* pbb   = (const float*)d_in[22];
  const float* ulW   = (const float*)d_in[23];
  const float* ulb   = (const float*)d_in[24];

  float* ws = (float*)d_ws;
  int*   ip = (int*)(ws + OFF_INT);
  if (ws_size < WS_FLOATS * sizeof(float)) return;

  unsigned short* wfrag   = (unsigned short*)(ws + OFF_WFRAG);
  unsigned short* linfrag = (unsigned short*)(ws + OFF_LINFRAG);
  unsigned short* ulfrag  = linfrag + 32768;
  unsigned short* OUTF  = (unsigned short*)(ws + OFF_OUTF);
  unsigned short* OUTB  = (unsigned short*)(ws + OFF_OUTB);
  unsigned short* POUTF = (unsigned short*)(ws + OFF_POUTF);
  unsigned short* POUTB = (unsigned short*)(ws + OFF_POUTB);
  unsigned short* TOKF16 = (unsigned short*)(ws + OFF_TOKFEAT);
  unsigned short* EMB16  = (unsigned short*)(ws + OFF_OUTLIN); // overlay

  prep_kernel<<<1332, 256, 0, stream>>>(tWif, tWhf, tWib, tWhb,
                                        pWif, pWhf, pWib, pWhb,
                                        linW, ulW, emb, units, paths, upd, ppd,
                                        ws, ip);

  lstm_kernel<0><<<dim3(128, 2), 1024, 0, stream>>>(
      wfrag, tbf, tbb, EMB16, units, ip /*tok_len*/,
      nullptr, nullptr, nullptr, OUTF, OUTB);

  gemm_mfma<1><<<1024, 256, 0, stream>>>(
      OUTF, OUTB, ip /*tok_len*/, linfrag, linb,
      (void*)(ws + OFF_OUTLIN), ws + OFF_SCORES, lng, lnb, attw, attb, units, NUNITS);

  softmax_feat_kernel<<<1024, 128, 0, stream>>>(
      ws + OFF_SCORES, (const unsigned short*)(ws + OFF_OUTLIN), TOKF16);

  lstm_kernel<1><<<dim3(128, 2), 1024, 0, stream>>>(
      wfrag, pbf, pbb, TOKF16, paths, ip + 5120 /*p_len*/,
      ip + 4096 /*fe*/, ip + 6144 /*off_p*/, ip + 7168 /*un_p*/,
      POUTF, POUTB);

  gemm_mfma<0><<<512, 256, 0, stream>>>(
      POUTF, POUTB, ip + 5120 /*p_len*/, ulfrag, ulb,
      (void*)d_out, nullptr, nullptr, nullptr, nullptr, nullptr, nullptr, NPATHS);
}